// Round 5
// baseline (611.393 us; speedup 1.0000x reference)
//
#include <hip/hip_runtime.h>

// LSTM-GCN single step from (H=0, C=0).
// Collapsed math: Fg gate dead (C_prev=0), cheb(H,..)=bh, peephole wc[0],wc[1] dead.
//
// R9: R6/R7/R8 all failed to pipeline the gather at HIP source level (VGPR=20,
// 303 us, one rec->x->ds_add chain in flight regardless of named scalars /
// clamped indices / guard-free bodies) -- the scheduler sinks loads to minimize
// pressure and nothing at source level overrides it. This round forces the
// pipeline at ISA level: records are LDS-staged (streaming copy, compiler
// pipelines that fine), then per half-wave batches of 8 x-row loads are issued
// from ONE asm volatile block ending in s_waitcnt vmcnt(0) (early-clobber
// outputs; consumers are data-dependent on the asm -> cannot be hoisted).

#define FDIM 32
#define MAX_N 100000
#define MAX_E 1600000
#define CBSH 6                                // 64 nodes per coarse bucket
#define CB 64
#define MAX_NB ((MAX_N + CB - 1) / CB)        // 1563 buckets max
#define NBLK 512                              // blocks in each edge pass
#define SCAN_TILE 1024                        // elements per scan block (256 thr x 4)
#define CHUNK 1024                            // records staged in LDS per block pass

__device__ float g_deg[MAX_N];                // degree -> dinv in place
__device__ int   g_part[MAX_NB * NBLK + 1];   // per-(bin,block) counts -> offsets
__device__ int   g_blk[1024];                 // scan block sums
__device__ uint2 g_rec[MAX_E];                // packed {src<<6|dst_low, nrm} by bucket
__device__ float g_tx1[MAX_N * FDIM];         // L_hat @ x

__global__ void zero_kernel(int n_nodes, int nbuck) {
    int i = blockIdx.x * blockDim.x + threadIdx.x;
    for (; i < n_nodes; i += gridDim.x * blockDim.x) g_deg[i] = 0.f;
    if (blockIdx.x == 0 && threadIdx.x == 0) g_part[nbuck * NBLK] = 0;  // scan sentinel
}

// One edge pass: deg[s] += w (global f32 atomic, fire-and-forget, self-loops
// excluded) and LDS coarse histogram of dst>>6, flushed NON-atomically to
// g_part[bin*NBLK + block].
__global__ __launch_bounds__(256) void hist_deg_kernel(const int* __restrict__ ei,
                                                       const float* __restrict__ w,
                                                       int E, int n_nodes, int nbuck,
                                                       int per_blk) {
    __shared__ int h[MAX_NB];
    for (int i = threadIdx.x; i < nbuck; i += 256) h[i] = 0;
    __syncthreads();
    int start = blockIdx.x * per_blk;
    int end = start + per_blk;
    if (end > E) end = E;
    for (int e = start + threadIdx.x; e < end; e += 256) {
        int s = ei[e];
        int d = ei[E + e];
        if ((unsigned)s >= (unsigned)n_nodes || (unsigned)d >= (unsigned)n_nodes) continue;
        if (s != d) unsafeAtomicAdd(&g_deg[s], w[e]);
        atomicAdd(&h[d >> CBSH], 1);          // LDS atomic
    }
    __syncthreads();
    for (int i = threadIdx.x; i < nbuck; i += 256)
        g_part[i * NBLK + blockIdx.x] = h[i]; // plain store, no atomics
}

__global__ void dinv_kernel(int n) {
    int i = blockIdx.x * blockDim.x + threadIdx.x;
    if (i >= n) return;
    float d = g_deg[i];
    g_deg[i] = (d > 0.f) ? rsqrtf(d) : 0.f;
}

// --- exclusive scan over g_part[0..n), 3 kernels (n = nbuck*NBLK + 1 <= ~800k) ---
__global__ __launch_bounds__(256) void scan1_kernel(int n) {
    __shared__ int sh[256];
    int tid = threadIdx.x;
    int base = blockIdx.x * SCAN_TILE + tid * 4;
    int v[4];
#pragma unroll
    for (int i = 0; i < 4; ++i) v[i] = (base + i < n) ? g_part[base + i] : 0;
    int tsum = v[0] + v[1] + v[2] + v[3];
    sh[tid] = tsum;
    __syncthreads();
    for (int off = 1; off < 256; off <<= 1) {
        int t = (tid >= off) ? sh[tid - off] : 0;
        __syncthreads();
        sh[tid] += t;
        __syncthreads();
    }
    if (tid == 255) g_blk[blockIdx.x] = sh[255];
    int run = sh[tid] - tsum;   // exclusive offset within block
#pragma unroll
    for (int i = 0; i < 4; ++i) {
        if (base + i < n) g_part[base + i] = run;
        run += v[i];
    }
}

__global__ __launch_bounds__(256) void scan2_kernel(int nb) {   // nb <= 1024
    __shared__ int sh[256];
    int tid = threadIdx.x;
    int base = tid * 4;
    int v[4];
#pragma unroll
    for (int i = 0; i < 4; ++i) v[i] = (base + i < nb) ? g_blk[base + i] : 0;
    int tsum = v[0] + v[1] + v[2] + v[3];
    sh[tid] = tsum;
    __syncthreads();
    for (int off = 1; off < 256; off <<= 1) {
        int t = (tid >= off) ? sh[tid - off] : 0;
        __syncthreads();
        sh[tid] += t;
        __syncthreads();
    }
    int run = sh[tid] - tsum;
#pragma unroll
    for (int i = 0; i < 4; ++i) {
        if (base + i < nb) g_blk[base + i] = run;
        run += v[i];
    }
}

__global__ void scan3_kernel(int n) {
    int off = g_blk[blockIdx.x];
    int base = blockIdx.x * SCAN_TILE + threadIdx.x * 4;
#pragma unroll
    for (int i = 0; i < 4; ++i) {
        int idx = base + i;
        if (idx < n) g_part[idx] += off;
    }
}

// Re-reads the IDENTICAL edge range as hist_deg_kernel; per-bin LDS cursors start
// at the scanned (bin,block) offsets, so record placement needs no global atomics.
__global__ __launch_bounds__(256) void scatter_kernel(const int* __restrict__ ei,
                                                      const float* __restrict__ w,
                                                      int E, int n_nodes, int nbuck,
                                                      int per_blk) {
    __shared__ int cur[MAX_NB];
    for (int i = threadIdx.x; i < nbuck; i += 256)
        cur[i] = g_part[i * NBLK + blockIdx.x];
    __syncthreads();
    int start = blockIdx.x * per_blk;
    int end = start + per_blk;
    if (end > E) end = E;
    for (int e = start + threadIdx.x; e < end; e += 256) {
        int s = ei[e];
        int d = ei[E + e];
        if ((unsigned)s >= (unsigned)n_nodes || (unsigned)d >= (unsigned)n_nodes) continue;
        float nrm = (s == d) ? 0.f : -g_deg[s] * w[e] * g_deg[d];  // g_deg holds dinv
        int pos = atomicAdd(&cur[d >> CBSH], 1);                   // LDS atomic
        g_rec[pos] = make_uint2(((unsigned)s << CBSH) | (unsigned)(d & (CB - 1)),
                                __float_as_uint(nrm));
    }
}

// One block per 64-node bucket. Records staged into LDS (coalesced streaming
// copy), then each half-wave (32 lanes = 32 features) consumes its contiguous
// slice in batches of 8: metadata via ds_read broadcast, then 8 x-row loads
// issued from ONE asm block ending in s_waitcnt vmcnt(0) -- the pipeline the
// HIP scheduler refused to form for three rounds. Accumulate via ds_add_f32
// into an 8 KB acc tile (lane f -> bank f, conflict-free), coalesced write-out.
__global__ __launch_bounds__(256) void bucket_gather_kernel(const float* __restrict__ x,
                                                            int n_nodes, int nbuck) {
    __shared__ float acc[CB * FDIM];   // 8 KB
    __shared__ uint2 srec[CHUNK];      // 8 KB
    int b = blockIdx.x;
    for (int i = threadIdx.x; i < CB * FDIM; i += 256) acc[i] = 0.f;
    int rs = g_part[b * NBLK];
    int re = g_part[(b + 1) * NBLK];   // b == nbuck-1 hits the sentinel (= total)
    int hh = threadIdx.x >> 5;         // 0..7 half-wave id
    int f  = threadIdx.x & 31;

    for (int base = rs; base < re; ) {
        int cnt = re - base; if (cnt > CHUNK) cnt = CHUNK;     // uniform per block
        __syncthreads();               // srec reuse + (1st iter) acc zero visible
        for (int t = threadIdx.x; t < cnt; t += 256) srec[t] = g_rec[base + t];
        __syncthreads();
        int per = (cnt + 7) >> 3;      // contiguous slice per half-wave
        int i0 = hh * per;
        int i1 = i0 + per; if (i1 > cnt) i1 = cnt;
        int i = i0;
        for (; i + 8 <= i1; i += 8) {
            uint2 r0 = srec[i+0], r1 = srec[i+1], r2 = srec[i+2], r3 = srec[i+3];
            uint2 r4 = srec[i+4], r5 = srec[i+5], r6 = srec[i+6], r7 = srec[i+7];
            const float* a0 = x + ((r0.x >> CBSH) << 5) + f;
            const float* a1 = x + ((r1.x >> CBSH) << 5) + f;
            const float* a2 = x + ((r2.x >> CBSH) << 5) + f;
            const float* a3 = x + ((r3.x >> CBSH) << 5) + f;
            const float* a4 = x + ((r4.x >> CBSH) << 5) + f;
            const float* a5 = x + ((r5.x >> CBSH) << 5) + f;
            const float* a6 = x + ((r6.x >> CBSH) << 5) + f;
            const float* a7 = x + ((r7.x >> CBSH) << 5) + f;
            float x0, x1, x2, x3, x4, x5, x6, x7;
            asm volatile(
                "global_load_dword %0, %8, off\n\t"
                "global_load_dword %1, %9, off\n\t"
                "global_load_dword %2, %10, off\n\t"
                "global_load_dword %3, %11, off\n\t"
                "global_load_dword %4, %12, off\n\t"
                "global_load_dword %5, %13, off\n\t"
                "global_load_dword %6, %14, off\n\t"
                "global_load_dword %7, %15, off\n\t"
                "s_waitcnt vmcnt(0)"
                : "=&v"(x0), "=&v"(x1), "=&v"(x2), "=&v"(x3),
                  "=&v"(x4), "=&v"(x5), "=&v"(x6), "=&v"(x7)
                : "v"(a0), "v"(a1), "v"(a2), "v"(a3),
                  "v"(a4), "v"(a5), "v"(a6), "v"(a7)
                : "memory");
            atomicAdd(&acc[(r0.x & (CB - 1)) * FDIM + f], __uint_as_float(r0.y) * x0);
            atomicAdd(&acc[(r1.x & (CB - 1)) * FDIM + f], __uint_as_float(r1.y) * x1);
            atomicAdd(&acc[(r2.x & (CB - 1)) * FDIM + f], __uint_as_float(r2.y) * x2);
            atomicAdd(&acc[(r3.x & (CB - 1)) * FDIM + f], __uint_as_float(r3.y) * x3);
            atomicAdd(&acc[(r4.x & (CB - 1)) * FDIM + f], __uint_as_float(r4.y) * x4);
            atomicAdd(&acc[(r5.x & (CB - 1)) * FDIM + f], __uint_as_float(r5.y) * x5);
            atomicAdd(&acc[(r6.x & (CB - 1)) * FDIM + f], __uint_as_float(r6.y) * x6);
            atomicAdd(&acc[(r7.x & (CB - 1)) * FDIM + f], __uint_as_float(r7.y) * x7);
        }
        for (; i < i1; ++i) {          // tail: < 8 records in this half's slice
            uint2 r = srec[i];
            float xv = x[(r.x >> CBSH) * FDIM + f];
            atomicAdd(&acc[(r.x & (CB - 1)) * FDIM + f], __uint_as_float(r.y) * xv);
        }
        base += cnt;
    }
    __syncthreads();
    int bno = b << CBSH;
    for (int row = hh; row < CB; row += 8) {
        int n = bno + row;
        if (n < n_nodes) g_tx1[n * FDIM + f] = acc[row * FDIM + f];
    }
}

// 8 nodes per 256-thread block; thread (node, j) computes output feature j of
// gates i, c, o. Weights for the 3 live gates staged in LDS (24 KB).
__global__ __launch_bounds__(256) void gates_kernel(
    const float* __restrict__ x,
    const float* __restrict__ Wx, const float* __restrict__ bx,
    const float* __restrict__ bh, const float* __restrict__ wc,
    const float* __restrict__ bg, const float* __restrict__ lin_w,
    const float* __restrict__ lin_b, float* __restrict__ out, int n_nodes) {
    __shared__ float Ws[3 * 2048];      // gates {i,c,o} x K=2 x 32x32
    __shared__ float xs[8 * FDIM];
    __shared__ float ts[8 * FDIM];

    for (int idx = threadIdx.x; idx < 2048; idx += 256) {
        Ws[idx]          = Wx[0 * 2048 + idx];
        Ws[2048 + idx]   = Wx[2 * 2048 + idx];
        Ws[4096 + idx]   = Wx[3 * 2048 + idx];
    }
    int node0 = blockIdx.x * 8;
    {
        int n = node0 + (threadIdx.x >> 5);
        int f = threadIdx.x & 31;
        if (n < n_nodes) {
            xs[threadIdx.x] = x[n * FDIM + f];
            ts[threadIdx.x] = g_tx1[n * FDIM + f];
        }
    }
    __syncthreads();

    int ln = threadIdx.x >> 5;
    int j  = threadIdx.x & 31;
    int n  = node0 + ln;
    if (n >= n_nodes) return;

    const float* xr = &xs[ln * FDIM];
    const float* tr = &ts[ln * FDIM];
    float acc_i = 0.f, acc_c = 0.f, acc_o = 0.f;
#pragma unroll
    for (int k = 0; k < 32; ++k) {
        float xv = xr[k], tv = tr[k];
        int o0 = k * 32 + j;
        acc_i += xv * Ws[o0]          + tv * Ws[1024 + o0];
        acc_c += xv * Ws[2048 + o0]   + tv * Ws[3072 + o0];
        acc_o += xv * Ws[4096 + o0]   + tv * Ws[5120 + o0];
    }
    float bi = bx[0 * 32 + j] + bh[0 * 32 + j] + bg[0 * 32 + j];
    float bc = bx[2 * 32 + j] + bh[2 * 32 + j] + bg[2 * 32 + j];
    float bo = bx[3 * 32 + j] + bh[3 * 32 + j] + bg[3 * 32 + j];

    float I = 1.f / (1.f + __expf(-(acc_i + bi)));
    float T = tanhf(acc_c + bc);
    float C = I * T;                                    // Fg*C_prev = 0
    float O = 1.f / (1.f + __expf(-(acc_o + bo + wc[2 * 32 + j] * C)));
    float H = O * tanhf(C);
    float r = fmaxf(H, 0.f) * lin_w[j];
#pragma unroll
    for (int m = 16; m > 0; m >>= 1) r += __shfl_xor(r, m, 32);
    if (j == 0) out[n] = r + lin_b[0];
}

extern "C" void kernel_launch(void* const* d_in, const int* in_sizes, int n_in,
                              void* d_out, int out_size, void* d_ws, size_t ws_size,
                              hipStream_t stream) {
    const float* x     = (const float*)d_in[0];
    const int*   ei    = (const int*)d_in[1];      // int32 on device
    const float* w     = (const float*)d_in[2];
    const float* Wx    = (const float*)d_in[3];
    const float* bx    = (const float*)d_in[4];
    // d_in[5] = Wh: unused (H=0)
    const float* bh    = (const float*)d_in[6];
    const float* wc    = (const float*)d_in[7];
    const float* bg    = (const float*)d_in[8];
    const float* lin_w = (const float*)d_in[9];
    const float* lin_b = (const float*)d_in[10];
    float*       out   = (float*)d_out;

    int n_nodes = in_sizes[0] / FDIM;
    if (n_nodes > MAX_N) n_nodes = MAX_N;
    int E = in_sizes[2];
    if (E > MAX_E) E = MAX_E;

    int nbuck   = (n_nodes + CB - 1) >> CBSH;            // 1563 for N=100k
    int per_blk = (E + NBLK - 1) / NBLK;                 // 3125 edges/block
    int n_scan  = nbuck * NBLK + 1;                      // 800257
    int nb_scan = (n_scan + SCAN_TILE - 1) / SCAN_TILE;  // 782 (<= 1024 for scan2)

    zero_kernel<<<512, 256, 0, stream>>>(n_nodes, nbuck);
    hist_deg_kernel<<<NBLK, 256, 0, stream>>>(ei, w, E, n_nodes, nbuck, per_blk);
    dinv_kernel<<<(n_nodes + 255) / 256, 256, 0, stream>>>(n_nodes);
    scan1_kernel<<<nb_scan, 256, 0, stream>>>(n_scan);
    scan2_kernel<<<1, 256, 0, stream>>>(nb_scan);
    scan3_kernel<<<nb_scan, 256, 0, stream>>>(n_scan);
    scatter_kernel<<<NBLK, 256, 0, stream>>>(ei, w, E, n_nodes, nbuck, per_blk);
    bucket_gather_kernel<<<nbuck, 256, 0, stream>>>(x, n_nodes, nbuck);
    gates_kernel<<<(n_nodes + 7) / 8, 256, 0, stream>>>(
        x, Wx, bx, bh, wc, bg, lin_w, lin_b, out, n_nodes);
}

// Round 6
// 570.595 us; speedup vs baseline: 1.0715x; 1.0715x over previous
//
#include <hip/hip_runtime.h>

// LSTM-GCN single step from (H=0, C=0).
// Collapsed math: Fg gate dead (C_prev=0), cheb(H,..)=bh, peephole wc[0],wc[1] dead.
//
// R10: per-wave MLP is NOT the gather's lever (R9 forced 8 loads + vmcnt(0) in
// asm -> 310 us, identical to the 1-deep chain). The invariant across all four
// gather variants is the TINY GRID: 1563 blocks / 6252 waves for 8192 wave
// slots, draining as buckets finish (occupancy 42%). R4's CSR gather (12.5k
// blocks) was ~3x faster on the same access pattern. Fix: SPLIT=4 sub-blocks
// per bucket (grid 6252, sustained 32 waves/CU), each accumulating a private
// 8KB LDS partial and writing it coalesced to g_partial; the 4-way merge is
// fused into gates_kernel (reads 4 coalesced partial rows instead of g_tx1).

#define FDIM 32
#define MAX_N 100000
#define MAX_E 1600000
#define CBSH 6                                // 64 nodes per coarse bucket
#define CB 64
#define MAX_NB ((MAX_N + CB - 1) / CB)        // 1563 buckets max
#define NBLK 512                              // blocks in each edge pass
#define SCAN_TILE 1024                        // elements per scan block (256 thr x 4)
#define SPLIT 4                               // sub-blocks per bucket in the gather

__device__ float g_deg[MAX_N];                // degree -> dinv in place
__device__ int   g_part[MAX_NB * NBLK + 1];   // per-(bin,block) counts -> offsets
__device__ int   g_blk[1024];                 // scan block sums
__device__ uint2 g_rec[MAX_E];                // packed {src<<6|dst_low, nrm} by bucket
__device__ float g_partial[MAX_NB * SPLIT * CB * FDIM];  // 51.2 MB partial tiles

__global__ void zero_kernel(int n_nodes, int nbuck) {
    int i = blockIdx.x * blockDim.x + threadIdx.x;
    for (; i < n_nodes; i += gridDim.x * blockDim.x) g_deg[i] = 0.f;
    if (blockIdx.x == 0 && threadIdx.x == 0) g_part[nbuck * NBLK] = 0;  // scan sentinel
}

// One edge pass: deg[s] += w (global f32 atomic, fire-and-forget, self-loops
// excluded) and LDS coarse histogram of dst>>6, flushed NON-atomically to
// g_part[bin*NBLK + block].
__global__ __launch_bounds__(256) void hist_deg_kernel(const int* __restrict__ ei,
                                                       const float* __restrict__ w,
                                                       int E, int n_nodes, int nbuck,
                                                       int per_blk) {
    __shared__ int h[MAX_NB];
    for (int i = threadIdx.x; i < nbuck; i += 256) h[i] = 0;
    __syncthreads();
    int start = blockIdx.x * per_blk;
    int end = start + per_blk;
    if (end > E) end = E;
    for (int e = start + threadIdx.x; e < end; e += 256) {
        int s = ei[e];
        int d = ei[E + e];
        if ((unsigned)s >= (unsigned)n_nodes || (unsigned)d >= (unsigned)n_nodes) continue;
        if (s != d) unsafeAtomicAdd(&g_deg[s], w[e]);
        atomicAdd(&h[d >> CBSH], 1);          // LDS atomic
    }
    __syncthreads();
    for (int i = threadIdx.x; i < nbuck; i += 256)
        g_part[i * NBLK + blockIdx.x] = h[i]; // plain store, no atomics
}

__global__ void dinv_kernel(int n) {
    int i = blockIdx.x * blockDim.x + threadIdx.x;
    if (i >= n) return;
    float d = g_deg[i];
    g_deg[i] = (d > 0.f) ? rsqrtf(d) : 0.f;
}

// --- exclusive scan over g_part[0..n), 3 kernels (n = nbuck*NBLK + 1 <= ~800k) ---
__global__ __launch_bounds__(256) void scan1_kernel(int n) {
    __shared__ int sh[256];
    int tid = threadIdx.x;
    int base = blockIdx.x * SCAN_TILE + tid * 4;
    int v[4];
#pragma unroll
    for (int i = 0; i < 4; ++i) v[i] = (base + i < n) ? g_part[base + i] : 0;
    int tsum = v[0] + v[1] + v[2] + v[3];
    sh[tid] = tsum;
    __syncthreads();
    for (int off = 1; off < 256; off <<= 1) {
        int t = (tid >= off) ? sh[tid - off] : 0;
        __syncthreads();
        sh[tid] += t;
        __syncthreads();
    }
    if (tid == 255) g_blk[blockIdx.x] = sh[255];
    int run = sh[tid] - tsum;   // exclusive offset within block
#pragma unroll
    for (int i = 0; i < 4; ++i) {
        if (base + i < n) g_part[base + i] = run;
        run += v[i];
    }
}

__global__ __launch_bounds__(256) void scan2_kernel(int nb) {   // nb <= 1024
    __shared__ int sh[256];
    int tid = threadIdx.x;
    int base = tid * 4;
    int v[4];
#pragma unroll
    for (int i = 0; i < 4; ++i) v[i] = (base + i < nb) ? g_blk[base + i] : 0;
    int tsum = v[0] + v[1] + v[2] + v[3];
    sh[tid] = tsum;
    __syncthreads();
    for (int off = 1; off < 256; off <<= 1) {
        int t = (tid >= off) ? sh[tid - off] : 0;
        __syncthreads();
        sh[tid] += t;
        __syncthreads();
    }
    int run = sh[tid] - tsum;
#pragma unroll
    for (int i = 0; i < 4; ++i) {
        if (base + i < nb) g_blk[base + i] = run;
        run += v[i];
    }
}

__global__ void scan3_kernel(int n) {
    int off = g_blk[blockIdx.x];
    int base = blockIdx.x * SCAN_TILE + threadIdx.x * 4;
#pragma unroll
    for (int i = 0; i < 4; ++i) {
        int idx = base + i;
        if (idx < n) g_part[idx] += off;
    }
}

// Re-reads the IDENTICAL edge range as hist_deg_kernel; per-bin LDS cursors start
// at the scanned (bin,block) offsets, so record placement needs no global atomics.
__global__ __launch_bounds__(256) void scatter_kernel(const int* __restrict__ ei,
                                                      const float* __restrict__ w,
                                                      int E, int n_nodes, int nbuck,
                                                      int per_blk) {
    __shared__ int cur[MAX_NB];
    for (int i = threadIdx.x; i < nbuck; i += 256)
        cur[i] = g_part[i * NBLK + blockIdx.x];
    __syncthreads();
    int start = blockIdx.x * per_blk;
    int end = start + per_blk;
    if (end > E) end = E;
    for (int e = start + threadIdx.x; e < end; e += 256) {
        int s = ei[e];
        int d = ei[E + e];
        if ((unsigned)s >= (unsigned)n_nodes || (unsigned)d >= (unsigned)n_nodes) continue;
        float nrm = (s == d) ? 0.f : -g_deg[s] * w[e] * g_deg[d];  // g_deg holds dinv
        int pos = atomicAdd(&cur[d >> CBSH], 1);                   // LDS atomic
        g_rec[pos] = make_uint2(((unsigned)s << CBSH) | (unsigned)(d & (CB - 1)),
                                __float_as_uint(nrm));
    }
}

// SPLIT=4 sub-blocks per 64-node bucket; each accumulates its quarter of the
// bucket's records into a PRIVATE 8 KB LDS tile (ds_add_f32, lane f -> bank f,
// conflict-free) and writes the 2048-float partial coalesced to g_partial.
// Grid = nbuck*4 = 6252 blocks -> sustained ~32 waves/CU (the R5-R9 gathers
// ran 1563 blocks and were concurrency-starved at 42% occupancy).
__global__ __launch_bounds__(256) void split_gather_kernel(const float* __restrict__ x,
                                                           int n_nodes, int nbuck) {
    __shared__ float acc[CB * FDIM];   // 8 KB
    int b = blockIdx.x >> 2;           // bucket
    int u = blockIdx.x & 3;            // sub-block within bucket
    for (int i = threadIdx.x; i < CB * FDIM; i += 256) acc[i] = 0.f;
    int rs = g_part[b * NBLK];
    int re = g_part[(b + 1) * NBLK];   // b == nbuck-1 hits the sentinel (= total)
    int cnt = re - rs;
    int q = (cnt + SPLIT - 1) / SPLIT;
    int s0 = rs + u * q; if (s0 > re) s0 = re;
    int s1 = s0 + q;     if (s1 > re) s1 = re;
    __syncthreads();

    int hh = threadIdx.x >> 5;         // 0..7 half-wave id
    int f  = threadIdx.x & 31;
    int m = s1 - s0;
    int per = (m + 7) >> 3;            // contiguous slice per half-wave
    int i0 = s0 + hh * per;
    int i1 = i0 + per; if (i1 > s1) i1 = s1;

    int i = i0;
    for (; i + 4 <= i1; i += 4) {      // guard-free main body
        uint2 r0 = g_rec[i];
        uint2 r1 = g_rec[i + 1];
        uint2 r2 = g_rec[i + 2];
        uint2 r3 = g_rec[i + 3];
        float x0 = x[(r0.x >> CBSH) * FDIM + f];
        float x1 = x[(r1.x >> CBSH) * FDIM + f];
        float x2 = x[(r2.x >> CBSH) * FDIM + f];
        float x3 = x[(r3.x >> CBSH) * FDIM + f];
        atomicAdd(&acc[(r0.x & (CB - 1)) * FDIM + f], __uint_as_float(r0.y) * x0);
        atomicAdd(&acc[(r1.x & (CB - 1)) * FDIM + f], __uint_as_float(r1.y) * x1);
        atomicAdd(&acc[(r2.x & (CB - 1)) * FDIM + f], __uint_as_float(r2.y) * x2);
        atomicAdd(&acc[(r3.x & (CB - 1)) * FDIM + f], __uint_as_float(r3.y) * x3);
    }
    for (; i < i1; ++i) {              // tail
        uint2 r = g_rec[i];
        float xv = x[(r.x >> CBSH) * FDIM + f];
        atomicAdd(&acc[(r.x & (CB - 1)) * FDIM + f], __uint_as_float(r.y) * xv);
    }
    __syncthreads();
    float* dst = g_partial + (size_t)blockIdx.x * (CB * FDIM);
    for (int t = threadIdx.x; t < CB * FDIM; t += 256) dst[t] = acc[t];  // coalesced
}

// 8 nodes per 256-thread block; thread (node, j) computes output feature j of
// gates i, c, o. Weights for the 3 live gates staged in LDS (24 KB).
// Merge of the 4 gather partials is fused here: ts = sum of 4 coalesced rows
// (a gates block never straddles a bucket: 8 | 64).
__global__ __launch_bounds__(256) void gates_kernel(
    const float* __restrict__ x,
    const float* __restrict__ Wx, const float* __restrict__ bx,
    const float* __restrict__ bh, const float* __restrict__ wc,
    const float* __restrict__ bg, const float* __restrict__ lin_w,
    const float* __restrict__ lin_b, float* __restrict__ out, int n_nodes) {
    __shared__ float Ws[3 * 2048];      // gates {i,c,o} x K=2 x 32x32
    __shared__ float xs[8 * FDIM];
    __shared__ float ts[8 * FDIM];

    for (int idx = threadIdx.x; idx < 2048; idx += 256) {
        Ws[idx]          = Wx[0 * 2048 + idx];
        Ws[2048 + idx]   = Wx[2 * 2048 + idx];
        Ws[4096 + idx]   = Wx[3 * 2048 + idx];
    }
    int node0 = blockIdx.x * 8;
    {
        int n = node0 + (threadIdx.x >> 5);
        int f = threadIdx.x & 31;
        if (n < n_nodes) {
            xs[threadIdx.x] = x[n * FDIM + f];
            int b   = n >> CBSH;
            int row = n & (CB - 1);
            size_t p = ((size_t)b * SPLIT) * (CB * FDIM) + row * FDIM + f;
            ts[threadIdx.x] = g_partial[p]
                            + g_partial[p + 1 * (CB * FDIM)]
                            + g_partial[p + 2 * (CB * FDIM)]
                            + g_partial[p + 3 * (CB * FDIM)];
        }
    }
    __syncthreads();

    int ln = threadIdx.x >> 5;
    int j  = threadIdx.x & 31;
    int n  = node0 + ln;
    if (n >= n_nodes) return;

    const float* xr = &xs[ln * FDIM];
    const float* tr = &ts[ln * FDIM];
    float acc_i = 0.f, acc_c = 0.f, acc_o = 0.f;
#pragma unroll
    for (int k = 0; k < 32; ++k) {
        float xv = xr[k], tv = tr[k];
        int o0 = k * 32 + j;
        acc_i += xv * Ws[o0]          + tv * Ws[1024 + o0];
        acc_c += xv * Ws[2048 + o0]   + tv * Ws[3072 + o0];
        acc_o += xv * Ws[4096 + o0]   + tv * Ws[5120 + o0];
    }
    float bi = bx[0 * 32 + j] + bh[0 * 32 + j] + bg[0 * 32 + j];
    float bc = bx[2 * 32 + j] + bh[2 * 32 + j] + bg[2 * 32 + j];
    float bo = bx[3 * 32 + j] + bh[3 * 32 + j] + bg[3 * 32 + j];

    float I = 1.f / (1.f + __expf(-(acc_i + bi)));
    float T = tanhf(acc_c + bc);
    float C = I * T;                                    // Fg*C_prev = 0
    float O = 1.f / (1.f + __expf(-(acc_o + bo + wc[2 * 32 + j] * C)));
    float H = O * tanhf(C);
    float r = fmaxf(H, 0.f) * lin_w[j];
#pragma unroll
    for (int m = 16; m > 0; m >>= 1) r += __shfl_xor(r, m, 32);
    if (j == 0) out[n] = r + lin_b[0];
}

extern "C" void kernel_launch(void* const* d_in, const int* in_sizes, int n_in,
                              void* d_out, int out_size, void* d_ws, size_t ws_size,
                              hipStream_t stream) {
    const float* x     = (const float*)d_in[0];
    const int*   ei    = (const int*)d_in[1];      // int32 on device
    const float* w     = (const float*)d_in[2];
    const float* Wx    = (const float*)d_in[3];
    const float* bx    = (const float*)d_in[4];
    // d_in[5] = Wh: unused (H=0)
    const float* bh    = (const float*)d_in[6];
    const float* wc    = (const float*)d_in[7];
    const float* bg    = (const float*)d_in[8];
    const float* lin_w = (const float*)d_in[9];
    const float* lin_b = (const float*)d_in[10];
    float*       out   = (float*)d_out;

    int n_nodes = in_sizes[0] / FDIM;
    if (n_nodes > MAX_N) n_nodes = MAX_N;
    int E = in_sizes[2];
    if (E > MAX_E) E = MAX_E;

    int nbuck   = (n_nodes + CB - 1) >> CBSH;            // 1563 for N=100k
    int per_blk = (E + NBLK - 1) / NBLK;                 // 3125 edges/block
    int n_scan  = nbuck * NBLK + 1;                      // 800257
    int nb_scan = (n_scan + SCAN_TILE - 1) / SCAN_TILE;  // 782 (<= 1024 for scan2)

    zero_kernel<<<512, 256, 0, stream>>>(n_nodes, nbuck);
    hist_deg_kernel<<<NBLK, 256, 0, stream>>>(ei, w, E, n_nodes, nbuck, per_blk);
    dinv_kernel<<<(n_nodes + 255) / 256, 256, 0, stream>>>(n_nodes);
    scan1_kernel<<<nb_scan, 256, 0, stream>>>(n_scan);
    scan2_kernel<<<1, 256, 0, stream>>>(nb_scan);
    scan3_kernel<<<nb_scan, 256, 0, stream>>>(n_scan);
    scatter_kernel<<<NBLK, 256, 0, stream>>>(ei, w, E, n_nodes, nbuck, per_blk);
    split_gather_kernel<<<nbuck * SPLIT, 256, 0, stream>>>(x, n_nodes, nbuck);
    gates_kernel<<<(n_nodes + 7) / 8, 256, 0, stream>>>(
        x, Wx, bx, bh, wc, bg, lin_w, lin_b, out, n_nodes);
}

// Round 7
// 363.747 us; speedup vs baseline: 1.6808x; 1.5687x over previous
//
#include <hip/hip_runtime.h>

// LSTM-GCN single step from (H=0, C=0).
// Collapsed math: Fg gate dead (C_prev=0), cheb(H,..)=bh, peephole wc[0],wc[1] dead.
//
// R11: five gather variants (R5-R10) all ran 270-317 us; R4's CSR gather did the
// SAME 1.6M random x-line loads in <=140 us. Diff: R4 accumulated in REGISTERS
// (no ds_add in the loop -- LDS atomics are side-effects the scheduler won't
// hoist next-iteration loads across, which is why VGPR kept collapsing) and ran
// one half-wave per NODE (100k streams). This round rebuilds R4's gather on top
// of the atomic-free sort: new fine_sort kernel turns bucket-sorted records
// into per-node CSR (g_row + g_src2/g_nrm2) via LDS count + 64-lane shfl scan +
// LDS-cursor reorder; gather is R4's kernel verbatim; gates reads g_tx1 again.

#define FDIM 32
#define MAX_N 100000
#define MAX_E 1600000
#define CBSH 6                                // 64 nodes per coarse bucket
#define CB 64
#define MAX_NB ((MAX_N + CB - 1) / CB)        // 1563 buckets max
#define NBLK 512                              // blocks in each edge pass
#define SCAN_TILE 1024                        // elements per scan block (256 thr x 4)

__device__ float g_deg[MAX_N];                // degree -> dinv in place
__device__ int   g_part[MAX_NB * NBLK + 1];   // per-(bin,block) counts -> offsets
__device__ int   g_blk[1024];                 // scan block sums
__device__ uint2 g_rec[MAX_E];                // packed {src<<6|dst_low, nrm} by bucket
__device__ int   g_row[MAX_N + 1];            // per-node CSR row starts (absolute)
__device__ int   g_src2[MAX_E];               // CSR: src per edge, node-sorted
__device__ float g_nrm2[MAX_E];               // CSR: nrm per edge, node-sorted
__device__ float g_tx1[MAX_N * FDIM];         // L_hat @ x

__global__ void zero_kernel(int n_nodes, int nbuck) {
    int i = blockIdx.x * blockDim.x + threadIdx.x;
    for (; i < n_nodes; i += gridDim.x * blockDim.x) g_deg[i] = 0.f;
    if (blockIdx.x == 0 && threadIdx.x == 0) g_part[nbuck * NBLK] = 0;  // scan sentinel
}

// One edge pass: deg[s] += w (global f32 atomic, fire-and-forget, self-loops
// excluded) and LDS coarse histogram of dst>>6, flushed NON-atomically to
// g_part[bin*NBLK + block].
__global__ __launch_bounds__(256) void hist_deg_kernel(const int* __restrict__ ei,
                                                       const float* __restrict__ w,
                                                       int E, int n_nodes, int nbuck,
                                                       int per_blk) {
    __shared__ int h[MAX_NB];
    for (int i = threadIdx.x; i < nbuck; i += 256) h[i] = 0;
    __syncthreads();
    int start = blockIdx.x * per_blk;
    int end = start + per_blk;
    if (end > E) end = E;
    for (int e = start + threadIdx.x; e < end; e += 256) {
        int s = ei[e];
        int d = ei[E + e];
        if ((unsigned)s >= (unsigned)n_nodes || (unsigned)d >= (unsigned)n_nodes) continue;
        if (s != d) unsafeAtomicAdd(&g_deg[s], w[e]);
        atomicAdd(&h[d >> CBSH], 1);          // LDS atomic
    }
    __syncthreads();
    for (int i = threadIdx.x; i < nbuck; i += 256)
        g_part[i * NBLK + blockIdx.x] = h[i]; // plain store, no atomics
}

__global__ void dinv_kernel(int n) {
    int i = blockIdx.x * blockDim.x + threadIdx.x;
    if (i >= n) return;
    float d = g_deg[i];
    g_deg[i] = (d > 0.f) ? rsqrtf(d) : 0.f;
}

// --- exclusive scan over g_part[0..n), 3 kernels (n = nbuck*NBLK + 1 <= ~800k) ---
__global__ __launch_bounds__(256) void scan1_kernel(int n) {
    __shared__ int sh[256];
    int tid = threadIdx.x;
    int base = blockIdx.x * SCAN_TILE + tid * 4;
    int v[4];
#pragma unroll
    for (int i = 0; i < 4; ++i) v[i] = (base + i < n) ? g_part[base + i] : 0;
    int tsum = v[0] + v[1] + v[2] + v[3];
    sh[tid] = tsum;
    __syncthreads();
    for (int off = 1; off < 256; off <<= 1) {
        int t = (tid >= off) ? sh[tid - off] : 0;
        __syncthreads();
        sh[tid] += t;
        __syncthreads();
    }
    if (tid == 255) g_blk[blockIdx.x] = sh[255];
    int run = sh[tid] - tsum;   // exclusive offset within block
#pragma unroll
    for (int i = 0; i < 4; ++i) {
        if (base + i < n) g_part[base + i] = run;
        run += v[i];
    }
}

__global__ __launch_bounds__(256) void scan2_kernel(int nb) {   // nb <= 1024
    __shared__ int sh[256];
    int tid = threadIdx.x;
    int base = tid * 4;
    int v[4];
#pragma unroll
    for (int i = 0; i < 4; ++i) v[i] = (base + i < nb) ? g_blk[base + i] : 0;
    int tsum = v[0] + v[1] + v[2] + v[3];
    sh[tid] = tsum;
    __syncthreads();
    for (int off = 1; off < 256; off <<= 1) {
        int t = (tid >= off) ? sh[tid - off] : 0;
        __syncthreads();
        sh[tid] += t;
        __syncthreads();
    }
    int run = sh[tid] - tsum;
#pragma unroll
    for (int i = 0; i < 4; ++i) {
        if (base + i < nb) g_blk[base + i] = run;
        run += v[i];
    }
}

__global__ void scan3_kernel(int n) {
    int off = g_blk[blockIdx.x];
    int base = blockIdx.x * SCAN_TILE + threadIdx.x * 4;
#pragma unroll
    for (int i = 0; i < 4; ++i) {
        int idx = base + i;
        if (idx < n) g_part[idx] += off;
    }
}

// Re-reads the IDENTICAL edge range as hist_deg_kernel; per-bin LDS cursors start
// at the scanned (bin,block) offsets, so record placement needs no global atomics.
__global__ __launch_bounds__(256) void scatter_kernel(const int* __restrict__ ei,
                                                      const float* __restrict__ w,
                                                      int E, int n_nodes, int nbuck,
                                                      int per_blk) {
    __shared__ int cur[MAX_NB];
    for (int i = threadIdx.x; i < nbuck; i += 256)
        cur[i] = g_part[i * NBLK + blockIdx.x];
    __syncthreads();
    int start = blockIdx.x * per_blk;
    int end = start + per_blk;
    if (end > E) end = E;
    for (int e = start + threadIdx.x; e < end; e += 256) {
        int s = ei[e];
        int d = ei[E + e];
        if ((unsigned)s >= (unsigned)n_nodes || (unsigned)d >= (unsigned)n_nodes) continue;
        float nrm = (s == d) ? 0.f : -g_deg[s] * w[e] * g_deg[d];  // g_deg holds dinv
        int pos = atomicAdd(&cur[d >> CBSH], 1);                   // LDS atomic
        g_rec[pos] = make_uint2(((unsigned)s << CBSH) | (unsigned)(d & (CB - 1)),
                                __float_as_uint(nrm));
    }
}

// One block per bucket: count the 64 local nodes (LDS), 64-lane shfl exclusive
// scan, write ABSOLUTE per-node row starts to g_row, then reorder the bucket's
// records into per-node order as split g_src2/g_nrm2 (R4's CSR layout). All
// placement atomics are LDS; writes land in a <=4KB window (L2-resident).
__global__ __launch_bounds__(256) void fine_sort_kernel(int E, int n_nodes, int nbuck) {
    __shared__ int cnt[CB];
    __shared__ int cur[CB];
    int b = blockIdx.x;
    int rs = g_part[b * NBLK];
    int re = g_part[(b + 1) * NBLK];   // b == nbuck-1 hits the sentinel (= total)
    if (threadIdx.x < CB) cnt[threadIdx.x] = 0;
    __syncthreads();
    for (int i = rs + threadIdx.x; i < re; i += 256)
        atomicAdd(&cnt[g_rec[i].x & (CB - 1)], 1);
    __syncthreads();
    if (threadIdx.x < CB) {            // exactly one wave64: shfl scan
        int v = cnt[threadIdx.x];
        int inc = v;
#pragma unroll
        for (int off = 1; off < 64; off <<= 1) {
            int t = __shfl_up(inc, off, 64);
            if ((int)threadIdx.x >= off) inc += t;
        }
        int start = rs + (inc - v);    // exclusive
        cur[threadIdx.x] = start;
        int node = (b << CBSH) + threadIdx.x;
        if (node < n_nodes) g_row[node] = start;
    }
    if (b == nbuck - 1 && threadIdx.x == 0) g_row[n_nodes] = re;
    __syncthreads();
    for (int i = rs + threadIdx.x; i < re; i += 256) {
        uint2 r = g_rec[i];
        int pos = atomicAdd(&cur[r.x & (CB - 1)], 1);   // LDS atomic
        g_src2[pos] = (int)(r.x >> CBSH);
        g_nrm2[pos] = __uint_as_float(r.y);
    }
}

// R4's gather, verbatim: half-wave (32 lanes = 32 features) per node, REGISTER
// accumulator (no LDS atomics in the loop -> loads pipeline across iterations),
// guard-free 4-unroll, 12.5k blocks. Atomic-free by construction (CSR rows).
__global__ __launch_bounds__(256) void gather_kernel(const float* __restrict__ x,
                                                     int n_nodes) {
    int t = blockIdx.x * blockDim.x + threadIdx.x;
    int node = t >> 5;
    int f = t & 31;
    if (node >= n_nodes) return;
    int i = g_row[node];
    int end = g_row[node + 1];
    float acc = 0.f;
    for (; i + 4 <= end; i += 4) {
        int   s0 = g_src2[i],     s1 = g_src2[i + 1], s2 = g_src2[i + 2], s3 = g_src2[i + 3];
        float n0 = g_nrm2[i],     n1 = g_nrm2[i + 1], n2 = g_nrm2[i + 2], n3 = g_nrm2[i + 3];
        acc += n0 * x[s0 * FDIM + f] + n1 * x[s1 * FDIM + f]
             + n2 * x[s2 * FDIM + f] + n3 * x[s3 * FDIM + f];
    }
    for (; i < end; ++i) acc += g_nrm2[i] * x[g_src2[i] * FDIM + f];
    g_tx1[node * FDIM + f] = acc;
}

// 8 nodes per 256-thread block; thread (node, j) computes output feature j of
// gates i, c, o. Weights for the 3 live gates staged in LDS (24 KB).
__global__ __launch_bounds__(256) void gates_kernel(
    const float* __restrict__ x,
    const float* __restrict__ Wx, const float* __restrict__ bx,
    const float* __restrict__ bh, const float* __restrict__ wc,
    const float* __restrict__ bg, const float* __restrict__ lin_w,
    const float* __restrict__ lin_b, float* __restrict__ out, int n_nodes) {
    __shared__ float Ws[3 * 2048];      // gates {i,c,o} x K=2 x 32x32
    __shared__ float xs[8 * FDIM];
    __shared__ float ts[8 * FDIM];

    for (int idx = threadIdx.x; idx < 2048; idx += 256) {
        Ws[idx]          = Wx[0 * 2048 + idx];
        Ws[2048 + idx]   = Wx[2 * 2048 + idx];
        Ws[4096 + idx]   = Wx[3 * 2048 + idx];
    }
    int node0 = blockIdx.x * 8;
    {
        int n = node0 + (threadIdx.x >> 5);
        int f = threadIdx.x & 31;
        if (n < n_nodes) {
            xs[threadIdx.x] = x[n * FDIM + f];
            ts[threadIdx.x] = g_tx1[n * FDIM + f];
        }
    }
    __syncthreads();

    int ln = threadIdx.x >> 5;
    int j  = threadIdx.x & 31;
    int n  = node0 + ln;
    if (n >= n_nodes) return;

    const float* xr = &xs[ln * FDIM];
    const float* tr = &ts[ln * FDIM];
    float acc_i = 0.f, acc_c = 0.f, acc_o = 0.f;
#pragma unroll
    for (int k = 0; k < 32; ++k) {
        float xv = xr[k], tv = tr[k];
        int o0 = k * 32 + j;
        acc_i += xv * Ws[o0]          + tv * Ws[1024 + o0];
        acc_c += xv * Ws[2048 + o0]   + tv * Ws[3072 + o0];
        acc_o += xv * Ws[4096 + o0]   + tv * Ws[5120 + o0];
    }
    float bi = bx[0 * 32 + j] + bh[0 * 32 + j] + bg[0 * 32 + j];
    float bc = bx[2 * 32 + j] + bh[2 * 32 + j] + bg[2 * 32 + j];
    float bo = bx[3 * 32 + j] + bh[3 * 32 + j] + bg[3 * 32 + j];

    float I = 1.f / (1.f + __expf(-(acc_i + bi)));
    float T = tanhf(acc_c + bc);
    float C = I * T;                                    // Fg*C_prev = 0
    float O = 1.f / (1.f + __expf(-(acc_o + bo + wc[2 * 32 + j] * C)));
    float H = O * tanhf(C);
    float r = fmaxf(H, 0.f) * lin_w[j];
#pragma unroll
    for (int m = 16; m > 0; m >>= 1) r += __shfl_xor(r, m, 32);
    if (j == 0) out[n] = r + lin_b[0];
}

extern "C" void kernel_launch(void* const* d_in, const int* in_sizes, int n_in,
                              void* d_out, int out_size, void* d_ws, size_t ws_size,
                              hipStream_t stream) {
    const float* x     = (const float*)d_in[0];
    const int*   ei    = (const int*)d_in[1];      // int32 on device
    const float* w     = (const float*)d_in[2];
    const float* Wx    = (const float*)d_in[3];
    const float* bx    = (const float*)d_in[4];
    // d_in[5] = Wh: unused (H=0)
    const float* bh    = (const float*)d_in[6];
    const float* wc    = (const float*)d_in[7];
    const float* bg    = (const float*)d_in[8];
    const float* lin_w = (const float*)d_in[9];
    const float* lin_b = (const float*)d_in[10];
    float*       out   = (float*)d_out;

    int n_nodes = in_sizes[0] / FDIM;
    if (n_nodes > MAX_N) n_nodes = MAX_N;
    int E = in_sizes[2];
    if (E > MAX_E) E = MAX_E;

    int nbuck   = (n_nodes + CB - 1) >> CBSH;            // 1563 for N=100k
    int per_blk = (E + NBLK - 1) / NBLK;                 // 3125 edges/block
    int n_scan  = nbuck * NBLK + 1;                      // 800257
    int nb_scan = (n_scan + SCAN_TILE - 1) / SCAN_TILE;  // 782 (<= 1024 for scan2)

    zero_kernel<<<512, 256, 0, stream>>>(n_nodes, nbuck);
    hist_deg_kernel<<<NBLK, 256, 0, stream>>>(ei, w, E, n_nodes, nbuck, per_blk);
    dinv_kernel<<<(n_nodes + 255) / 256, 256, 0, stream>>>(n_nodes);
    scan1_kernel<<<nb_scan, 256, 0, stream>>>(n_scan);
    scan2_kernel<<<1, 256, 0, stream>>>(nb_scan);
    scan3_kernel<<<nb_scan, 256, 0, stream>>>(n_scan);
    scatter_kernel<<<NBLK, 256, 0, stream>>>(ei, w, E, n_nodes, nbuck, per_blk);
    fine_sort_kernel<<<nbuck, 256, 0, stream>>>(E, n_nodes, nbuck);
    {
        long long tot = (long long)n_nodes * 32;
        gather_kernel<<<(int)((tot + 255) / 256), 256, 0, stream>>>(x, n_nodes);
    }
    gates_kernel<<<(n_nodes + 7) / 8, 256, 0, stream>>>(
        x, Wx, bx, bh, wc, bg, lin_w, lin_b, out, n_nodes);
}

// Round 8
// 297.052 us; speedup vs baseline: 2.0582x; 1.2245x over previous
//
#include <hip/hip_runtime.h>

// LSTM-GCN single step from (H=0, C=0).
// Collapsed math: Fg gate dead (C_prev=0), cheb(H,..)=bh, peephole wc[0],wc[1] dead.
//
// R12: R11 confirmed register-accumulate + per-node streams (363 us). New top-2:
// gates (92.7 us: 24KB Ws staged 12500x, 20% occupancy, 1:1 ds_read:FMA) and
// hist_deg (91.4 us: WRITE 87MB = 1.6M global f32 deg atomics' write-through).
// Fix A: gates64 -- 64 nodes/block (staging amortized 8x, Ws reads reused
// across 8 per-thread nodes -> 22 ds_read per 48 FMA).
// Fix B: src-axis bucket sort sharing the one edge pass: dual LDS histograms
// (no global atomics anywhere), widened scan (VPT=8 over 1.6M), combined
// scatter (dst recs {src<<6|dloc, w} + src recs {sloc, w}), deg_sum produces
// dinv per bucket in LDS, fine_sort computes nrm using L2-resident dinv.
// Deletes zero/dinv kernels and one 19.2MB edge re-read.

#define FDIM 32
#define MAX_N 100000
#define MAX_E 1600000
#define CBSH 6                                // 64 nodes per coarse bucket
#define CB 64
#define MAX_NB ((MAX_N + CB - 1) / CB)        // 1563 buckets max
#define NBLK 512                              // blocks in each edge pass
#define SCAN_TILE 2048                        // elements per scan block (256 thr x 8)

__device__ float g_deg[MAX_N];                    // dinv (written by deg_sum)
__device__ int   g_part2[2 * MAX_NB * NBLK + 1];  // [dst bins | src bins] counts->offsets
__device__ int   g_blk[1024];                     // scan block sums
__device__ uint2 g_rec[MAX_E];                    // dst-sorted {src<<6|dst_loc, w}
__device__ uint2 g_srec[MAX_E];                   // src-sorted {src_loc, w}
__device__ int   g_row[MAX_N + 1];                // per-node CSR row starts
__device__ int   g_src2[MAX_E];                   // CSR: src per edge, node-sorted
__device__ float g_nrm2[MAX_E];                   // CSR: nrm per edge, node-sorted
__device__ float g_tx1[MAX_N * FDIM];             // L_hat @ x

// One edge pass, NO global atomics: dual LDS histograms of dst>>6 and src>>6,
// flushed non-atomically to g_part2[bin*NBLK + block] (src bins offset by nbuck).
__global__ __launch_bounds__(256) void hist2_kernel(const int* __restrict__ ei,
                                                    const float* __restrict__ w,
                                                    int E, int n_nodes, int nbuck,
                                                    int per_blk) {
    __shared__ int hd[MAX_NB];
    __shared__ int hs[MAX_NB];
    for (int i = threadIdx.x; i < nbuck; i += 256) { hd[i] = 0; hs[i] = 0; }
    __syncthreads();
    int start = blockIdx.x * per_blk;
    int end = start + per_blk;
    if (end > E) end = E;
    for (int e = start + threadIdx.x; e < end; e += 256) {
        int s = ei[e];
        int d = ei[E + e];
        if ((unsigned)s >= (unsigned)n_nodes || (unsigned)d >= (unsigned)n_nodes) continue;
        atomicAdd(&hd[d >> CBSH], 1);
        atomicAdd(&hs[s >> CBSH], 1);
    }
    __syncthreads();
    for (int i = threadIdx.x; i < nbuck; i += 256) {
        g_part2[i * NBLK + blockIdx.x] = hd[i];
        g_part2[(nbuck + i) * NBLK + blockIdx.x] = hs[i];
    }
    if (blockIdx.x == 0 && threadIdx.x == 0)
        g_part2[2 * nbuck * NBLK] = 0;        // scan sentinel
}

// --- exclusive scan over g_part2[0..n), 3 kernels, VPT=8 (n <= ~1.6M) ---
__global__ __launch_bounds__(256) void scan1_kernel(int n) {
    __shared__ int sh[256];
    int tid = threadIdx.x;
    int base = blockIdx.x * SCAN_TILE + tid * 8;
    int v[8];
#pragma unroll
    for (int i = 0; i < 8; ++i) v[i] = (base + i < n) ? g_part2[base + i] : 0;
    int tsum = 0;
#pragma unroll
    for (int i = 0; i < 8; ++i) tsum += v[i];
    sh[tid] = tsum;
    __syncthreads();
    for (int off = 1; off < 256; off <<= 1) {
        int t = (tid >= off) ? sh[tid - off] : 0;
        __syncthreads();
        sh[tid] += t;
        __syncthreads();
    }
    if (tid == 255) g_blk[blockIdx.x] = sh[255];
    int run = sh[tid] - tsum;   // exclusive offset within block
#pragma unroll
    for (int i = 0; i < 8; ++i) {
        if (base + i < n) g_part2[base + i] = run;
        run += v[i];
    }
}

__global__ __launch_bounds__(256) void scan2_kernel(int nb) {   // nb <= 1024
    __shared__ int sh[256];
    int tid = threadIdx.x;
    int base = tid * 4;
    int v[4];
#pragma unroll
    for (int i = 0; i < 4; ++i) v[i] = (base + i < nb) ? g_blk[base + i] : 0;
    int tsum = v[0] + v[1] + v[2] + v[3];
    sh[tid] = tsum;
    __syncthreads();
    for (int off = 1; off < 256; off <<= 1) {
        int t = (tid >= off) ? sh[tid - off] : 0;
        __syncthreads();
        sh[tid] += t;
        __syncthreads();
    }
    int run = sh[tid] - tsum;
#pragma unroll
    for (int i = 0; i < 4; ++i) {
        if (base + i < nb) g_blk[base + i] = run;
        run += v[i];
    }
}

__global__ void scan3_kernel(int n) {
    int off = g_blk[blockIdx.x];
    int base = blockIdx.x * SCAN_TILE + threadIdx.x * 8;
#pragma unroll
    for (int i = 0; i < 8; ++i) {
        int idx = base + i;
        if (idx < n) g_part2[idx] += off;
    }
}

// Re-reads the IDENTICAL edge range as hist2; dual LDS cursor sets start at the
// scanned per-(bin,block) offsets -> record placement needs no global atomics.
// Self-loops stored with w=0 (both sides): deg excludes them, nrm becomes 0.
__global__ __launch_bounds__(256) void scatter2_kernel(const int* __restrict__ ei,
                                                       const float* __restrict__ w,
                                                       int E, int n_nodes, int nbuck,
                                                       int per_blk) {
    __shared__ int curD[MAX_NB];
    __shared__ int curS[MAX_NB];
    for (int i = threadIdx.x; i < nbuck; i += 256) {
        curD[i] = g_part2[i * NBLK + blockIdx.x];
        curS[i] = g_part2[(nbuck + i) * NBLK + blockIdx.x];
    }
    __syncthreads();
    int start = blockIdx.x * per_blk;
    int end = start + per_blk;
    if (end > E) end = E;
    for (int e = start + threadIdx.x; e < end; e += 256) {
        int s = ei[e];
        int d = ei[E + e];
        if ((unsigned)s >= (unsigned)n_nodes || (unsigned)d >= (unsigned)n_nodes) continue;
        float w0 = (s == d) ? 0.f : w[e];
        int posD = atomicAdd(&curD[d >> CBSH], 1);            // LDS atomic
        g_rec[posD] = make_uint2(((unsigned)s << CBSH) | (unsigned)(d & (CB - 1)),
                                 __float_as_uint(w0));
        int posS = atomicAdd(&curS[s >> CBSH], 1) - E;        // src space is [E,2E)
        g_srec[posS] = make_uint2((unsigned)(s & (CB - 1)), __float_as_uint(w0));
    }
}

// One block per src bucket: LDS f32 accumulate w per local node, then write
// dinv = rsqrt(deg) directly. No global atomics.
__global__ __launch_bounds__(256) void deg_sum_kernel(int E, int n_nodes, int nbuck) {
    __shared__ float ldeg[CB];
    int b = blockIdx.x;
    int rs = g_part2[(nbuck + b) * NBLK] - E;
    int re = g_part2[(nbuck + b + 1) * NBLK] - E;   // b==nbuck-1 hits sentinel (2E)
    if (threadIdx.x < CB) ldeg[threadIdx.x] = 0.f;
    __syncthreads();
    for (int i = rs + threadIdx.x; i < re; i += 256) {
        uint2 r = g_srec[i];
        atomicAdd(&ldeg[r.x], __uint_as_float(r.y));   // LDS atomic
    }
    __syncthreads();
    if (threadIdx.x < CB) {
        int node = (b << CBSH) + threadIdx.x;
        if (node < n_nodes) {
            float dg = ldeg[threadIdx.x];
            g_deg[node] = (dg > 0.f) ? rsqrtf(dg) : 0.f;
        }
    }
}

// One block per dst bucket: count the <=64 local nodes (LDS), 64-lane shfl
// exclusive scan -> absolute g_row, then reorder records into per-node CSR
// (g_src2/g_nrm2), computing nrm = -dinv[s]*w*dinv[d] on the fly (dinv is
// 400 KB -> L2-resident; bucket-side dinv staged in LDS).
__global__ __launch_bounds__(256) void fine_sort_kernel(int E, int n_nodes, int nbuck) {
    __shared__ int cnt[CB];
    __shared__ int cur[CB];
    __shared__ float dv[CB];
    int b = blockIdx.x;
    int rs = g_part2[b * NBLK];
    int re = g_part2[(b + 1) * NBLK];   // b==nbuck-1 hits first src bin (= E)
    if (threadIdx.x < CB) {
        cnt[threadIdx.x] = 0;
        int node = (b << CBSH) + threadIdx.x;
        dv[threadIdx.x] = (node < n_nodes) ? g_deg[node] : 0.f;
    }
    __syncthreads();
    for (int i = rs + threadIdx.x; i < re; i += 256)
        atomicAdd(&cnt[g_rec[i].x & (CB - 1)], 1);
    __syncthreads();
    if (threadIdx.x < CB) {            // exactly one wave64: shfl scan
        int v = cnt[threadIdx.x];
        int inc = v;
#pragma unroll
        for (int off = 1; off < 64; off <<= 1) {
            int t = __shfl_up(inc, off, 64);
            if ((int)threadIdx.x >= off) inc += t;
        }
        int start = rs + (inc - v);    // exclusive
        cur[threadIdx.x] = start;
        int node = (b << CBSH) + threadIdx.x;
        if (node < n_nodes) g_row[node] = start;
    }
    if (b == nbuck - 1 && threadIdx.x == 0) g_row[n_nodes] = re;
    __syncthreads();
    for (int i = rs + threadIdx.x; i < re; i += 256) {
        uint2 r = g_rec[i];
        int s = (int)(r.x >> CBSH);
        int loc = r.x & (CB - 1);
        float nrm = -g_deg[s] * __uint_as_float(r.y) * dv[loc];
        int pos = atomicAdd(&cur[loc], 1);   // LDS atomic
        g_src2[pos] = s;
        g_nrm2[pos] = nrm;
    }
}

// R4's gather, verbatim: half-wave (32 lanes = 32 features) per node, REGISTER
// accumulator (loads pipeline across iterations), guard-free 4-unroll.
__global__ __launch_bounds__(256) void gather_kernel(const float* __restrict__ x,
                                                     int n_nodes) {
    int t = blockIdx.x * blockDim.x + threadIdx.x;
    int node = t >> 5;
    int f = t & 31;
    if (node >= n_nodes) return;
    int i = g_row[node];
    int end = g_row[node + 1];
    float acc = 0.f;
    for (; i + 4 <= end; i += 4) {
        int   s0 = g_src2[i],     s1 = g_src2[i + 1], s2 = g_src2[i + 2], s3 = g_src2[i + 3];
        float n0 = g_nrm2[i],     n1 = g_nrm2[i + 1], n2 = g_nrm2[i + 2], n3 = g_nrm2[i + 3];
        acc += n0 * x[s0 * FDIM + f] + n1 * x[s1 * FDIM + f]
             + n2 * x[s2 * FDIM + f] + n3 * x[s3 * FDIM + f];
    }
    for (; i < end; ++i) acc += g_nrm2[i] * x[g_src2[i] * FDIM + f];
    g_tx1[node * FDIM + f] = acc;
}

// 64 nodes per 256-thread block (grid = nbuck). Thread (grp, j) accumulates
// output feature j of gates i,c,o for 8 nodes -> the 6 Ws reads per k are
// reused across 8 nodes (22 ds_read per 48 FMA vs 1:1 before), and the 24 KB
// Ws staging is amortized 8x (1563 blocks instead of 12500).
__global__ __launch_bounds__(256) void gates64_kernel(
    const float* __restrict__ x,
    const float* __restrict__ Wx, const float* __restrict__ bx,
    const float* __restrict__ bh, const float* __restrict__ wc,
    const float* __restrict__ bg, const float* __restrict__ lin_w,
    const float* __restrict__ lin_b, float* __restrict__ out, int n_nodes) {
    __shared__ float Ws[3 * 2048];      // gates {i,c,o} x K=2 x 32x32 = 24 KB
    __shared__ float xs[CB * FDIM];     // 8 KB
    __shared__ float ts[CB * FDIM];     // 8 KB

    for (int idx = threadIdx.x; idx < 2048; idx += 256) {
        Ws[idx]          = Wx[0 * 2048 + idx];
        Ws[2048 + idx]   = Wx[2 * 2048 + idx];
        Ws[4096 + idx]   = Wx[3 * 2048 + idx];
    }
    int node0 = blockIdx.x * CB;
    for (int t = threadIdx.x; t < CB * FDIM; t += 256) {
        int n = node0 + (t >> 5);
        int f = t & 31;
        bool ok = (n < n_nodes);
        xs[t] = ok ? x[n * FDIM + f] : 0.f;
        ts[t] = ok ? g_tx1[n * FDIM + f] : 0.f;
    }
    __syncthreads();

    int j   = threadIdx.x & 31;
    int grp = threadIdx.x >> 5;         // 0..7, handles nodes grp*8 .. grp*8+7

    float ai0=0.f,ai1=0.f,ai2=0.f,ai3=0.f,ai4=0.f,ai5=0.f,ai6=0.f,ai7=0.f;
    float ac0=0.f,ac1=0.f,ac2=0.f,ac3=0.f,ac4=0.f,ac5=0.f,ac6=0.f,ac7=0.f;
    float ao0=0.f,ao1=0.f,ao2=0.f,ao3=0.f,ao4=0.f,ao5=0.f,ao6=0.f,ao7=0.f;
    const float* xr = &xs[(grp * 8) * FDIM];
    const float* tr = &ts[(grp * 8) * FDIM];
    for (int k = 0; k < 32; ++k) {
        int o0 = k * 32 + j;
        float wi0 = Ws[o0],        wi1 = Ws[1024 + o0];
        float wc0 = Ws[2048 + o0], wc1 = Ws[3072 + o0];
        float wo0 = Ws[4096 + o0], wo1 = Ws[5120 + o0];
#define GSTEP(m, AI, AC, AO)                                   \
        {   float xv = xr[m * FDIM + k], tv = tr[m * FDIM + k];\
            AI += xv * wi0 + tv * wi1;                         \
            AC += xv * wc0 + tv * wc1;                         \
            AO += xv * wo0 + tv * wo1; }
        GSTEP(0, ai0, ac0, ao0) GSTEP(1, ai1, ac1, ao1)
        GSTEP(2, ai2, ac2, ao2) GSTEP(3, ai3, ac3, ao3)
        GSTEP(4, ai4, ac4, ao4) GSTEP(5, ai5, ac5, ao5)
        GSTEP(6, ai6, ac6, ao6) GSTEP(7, ai7, ac7, ao7)
#undef GSTEP
    }

    float bi = bx[0 * 32 + j] + bh[0 * 32 + j] + bg[0 * 32 + j];
    float bc = bx[2 * 32 + j] + bh[2 * 32 + j] + bg[2 * 32 + j];
    float bo = bx[3 * 32 + j] + bh[3 * 32 + j] + bg[3 * 32 + j];
    float wcp = wc[2 * 32 + j];
    float lwj = lin_w[j];
    float lb0 = lin_b[0];

#define GOUT(m, AI, AC, AO)                                            \
    {   int n = node0 + grp * 8 + m;                                   \
        float I = 1.f / (1.f + __expf(-(AI + bi)));                    \
        float T = tanhf(AC + bc);                                      \
        float C = I * T;                                               \
        float O = 1.f / (1.f + __expf(-(AO + bo + wcp * C)));          \
        float H = O * tanhf(C);                                        \
        float r = fmaxf(H, 0.f) * lwj;                                 \
        _Pragma("unroll")                                              \
        for (int mm = 16; mm > 0; mm >>= 1) r += __shfl_xor(r, mm, 32);\
        if (j == 0 && n < n_nodes) out[n] = r + lb0; }
    GOUT(0, ai0, ac0, ao0) GOUT(1, ai1, ac1, ao1)
    GOUT(2, ai2, ac2, ao2) GOUT(3, ai3, ac3, ao3)
    GOUT(4, ai4, ac4, ao4) GOUT(5, ai5, ac5, ao5)
    GOUT(6, ai6, ac6, ao6) GOUT(7, ai7, ac7, ao7)
#undef GOUT
}

extern "C" void kernel_launch(void* const* d_in, const int* in_sizes, int n_in,
                              void* d_out, int out_size, void* d_ws, size_t ws_size,
                              hipStream_t stream) {
    const float* x     = (const float*)d_in[0];
    const int*   ei    = (const int*)d_in[1];      // int32 on device
    const float* w     = (const float*)d_in[2];
    const float* Wx    = (const float*)d_in[3];
    const float* bx    = (const float*)d_in[4];
    // d_in[5] = Wh: unused (H=0)
    const float* bh    = (const float*)d_in[6];
    const float* wc    = (const float*)d_in[7];
    const float* bg    = (const float*)d_in[8];
    const float* lin_w = (const float*)d_in[9];
    const float* lin_b = (const float*)d_in[10];
    float*       out   = (float*)d_out;

    int n_nodes = in_sizes[0] / FDIM;
    if (n_nodes > MAX_N) n_nodes = MAX_N;
    int E = in_sizes[2];
    if (E > MAX_E) E = MAX_E;

    int nbuck   = (n_nodes + CB - 1) >> CBSH;            // 1563 for N=100k
    int per_blk = (E + NBLK - 1) / NBLK;                 // 3125 edges/block
    int n_scan  = 2 * nbuck * NBLK + 1;                  // 1600513
    int nb_scan = (n_scan + SCAN_TILE - 1) / SCAN_TILE;  // 782 (<= 1024 for scan2)

    hist2_kernel<<<NBLK, 256, 0, stream>>>(ei, w, E, n_nodes, nbuck, per_blk);
    scan1_kernel<<<nb_scan, 256, 0, stream>>>(n_scan);
    scan2_kernel<<<1, 256, 0, stream>>>(nb_scan);
    scan3_kernel<<<nb_scan, 256, 0, stream>>>(n_scan);
    scatter2_kernel<<<NBLK, 256, 0, stream>>>(ei, w, E, n_nodes, nbuck, per_blk);
    deg_sum_kernel<<<nbuck, 256, 0, stream>>>(E, n_nodes, nbuck);
    fine_sort_kernel<<<nbuck, 256, 0, stream>>>(E, n_nodes, nbuck);
    {
        long long tot = (long long)n_nodes * 32;
        gather_kernel<<<(int)((tot + 255) / 256), 256, 0, stream>>>(x, n_nodes);
    }
    gates64_kernel<<<nbuck, 256, 0, stream>>>(
        x, Wx, bx, bh, wc, bg, lin_w, lin_b, out, n_nodes);
}

// Round 9
// 276.809 us; speedup vs baseline: 2.2087x; 1.0731x over previous
//
#include <hip/hip_runtime.h>

// LSTM-GCN single step from (H=0, C=0).
// Collapsed math: Fg gate dead (C_prev=0), cheb(H,..)=bh, peephole wc[0],wc[1] dead.
//
// R13: R12's scatter2 showed 3.7x write amplification (WRITE 95MB vs 25.6MB
// payload): per-(bin,block) runs were only ~2 records = 16B, so every 8B store
// hit its own 64B sector. Fix: CBSH 6->8 (256-node buckets, nbuck=391) -> runs
// of ~8 records = 64B, full-sector writes at unchanged NBLK=512. fine_sort/
// deg_sum move to 256-wide buckets (4-wave hierarchical scan); gates64 keeps
// its own 64-node blocks; scan shrinks to 400K entries.

#define FDIM 32
#define MAX_N 100000
#define MAX_E 1600000
#define CBSH 8                                // 256 nodes per coarse bucket
#define CB 256
#define MAX_NB ((MAX_N + CB - 1) / CB)        // 391 buckets max
#define NBLK 512                              // blocks in each edge pass
#define SCAN_TILE 2048                        // elements per scan block (256 thr x 8)
#define GNB 64                                // nodes per gates block

__device__ float g_deg[MAX_N];                    // dinv (written by deg_sum)
__device__ int   g_part2[2 * MAX_NB * NBLK + 1];  // [dst bins | src bins] counts->offsets
__device__ int   g_blk[1024];                     // scan block sums
__device__ uint2 g_rec[MAX_E];                    // dst-sorted {src<<8|dst_loc, w}
__device__ uint2 g_srec[MAX_E];                   // src-sorted {src_loc, w}
__device__ int   g_row[MAX_N + 1];                // per-node CSR row starts
__device__ int   g_src2[MAX_E];                   // CSR: src per edge, node-sorted
__device__ float g_nrm2[MAX_E];                   // CSR: nrm per edge, node-sorted
__device__ float g_tx1[MAX_N * FDIM];             // L_hat @ x

// One edge pass, NO global atomics: dual LDS histograms of dst>>8 and src>>8,
// flushed non-atomically to g_part2[bin*NBLK + block] (src bins offset by nbuck).
__global__ __launch_bounds__(256) void hist2_kernel(const int* __restrict__ ei,
                                                    int E, int n_nodes, int nbuck,
                                                    int per_blk) {
    __shared__ int hd[MAX_NB];
    __shared__ int hs[MAX_NB];
    for (int i = threadIdx.x; i < nbuck; i += 256) { hd[i] = 0; hs[i] = 0; }
    __syncthreads();
    int start = blockIdx.x * per_blk;
    int end = start + per_blk;
    if (end > E) end = E;
    for (int e = start + threadIdx.x; e < end; e += 256) {
        int s = ei[e];
        int d = ei[E + e];
        if ((unsigned)s >= (unsigned)n_nodes || (unsigned)d >= (unsigned)n_nodes) continue;
        atomicAdd(&hd[d >> CBSH], 1);
        atomicAdd(&hs[s >> CBSH], 1);
    }
    __syncthreads();
    for (int i = threadIdx.x; i < nbuck; i += 256) {
        g_part2[i * NBLK + blockIdx.x] = hd[i];
        g_part2[(nbuck + i) * NBLK + blockIdx.x] = hs[i];
    }
    if (blockIdx.x == 0 && threadIdx.x == 0)
        g_part2[2 * nbuck * NBLK] = 0;        // scan sentinel
}

// --- exclusive scan over g_part2[0..n), 3 kernels, VPT=8 (n ~ 400K) ---
__global__ __launch_bounds__(256) void scan1_kernel(int n) {
    __shared__ int sh[256];
    int tid = threadIdx.x;
    int base = blockIdx.x * SCAN_TILE + tid * 8;
    int v[8];
#pragma unroll
    for (int i = 0; i < 8; ++i) v[i] = (base + i < n) ? g_part2[base + i] : 0;
    int tsum = 0;
#pragma unroll
    for (int i = 0; i < 8; ++i) tsum += v[i];
    sh[tid] = tsum;
    __syncthreads();
    for (int off = 1; off < 256; off <<= 1) {
        int t = (tid >= off) ? sh[tid - off] : 0;
        __syncthreads();
        sh[tid] += t;
        __syncthreads();
    }
    if (tid == 255) g_blk[blockIdx.x] = sh[255];
    int run = sh[tid] - tsum;   // exclusive offset within block
#pragma unroll
    for (int i = 0; i < 8; ++i) {
        if (base + i < n) g_part2[base + i] = run;
        run += v[i];
    }
}

__global__ __launch_bounds__(256) void scan2_kernel(int nb) {   // nb <= 1024
    __shared__ int sh[256];
    int tid = threadIdx.x;
    int base = tid * 4;
    int v[4];
#pragma unroll
    for (int i = 0; i < 4; ++i) v[i] = (base + i < nb) ? g_blk[base + i] : 0;
    int tsum = v[0] + v[1] + v[2] + v[3];
    sh[tid] = tsum;
    __syncthreads();
    for (int off = 1; off < 256; off <<= 1) {
        int t = (tid >= off) ? sh[tid - off] : 0;
        __syncthreads();
        sh[tid] += t;
        __syncthreads();
    }
    int run = sh[tid] - tsum;
#pragma unroll
    for (int i = 0; i < 4; ++i) {
        if (base + i < nb) g_blk[base + i] = run;
        run += v[i];
    }
}

__global__ void scan3_kernel(int n) {
    int off = g_blk[blockIdx.x];
    int base = blockIdx.x * SCAN_TILE + threadIdx.x * 8;
#pragma unroll
    for (int i = 0; i < 8; ++i) {
        int idx = base + i;
        if (idx < n) g_part2[idx] += off;
    }
}

// Re-reads the IDENTICAL edge range as hist2; dual LDS cursor sets start at the
// scanned per-(bin,block) offsets -> record placement needs no global atomics.
// Runs are now ~8 records = 64B: full-sector contiguous stores.
// Self-loops stored with w=0 (both sides): deg excludes them, nrm becomes 0.
__global__ __launch_bounds__(256) void scatter2_kernel(const int* __restrict__ ei,
                                                       const float* __restrict__ w,
                                                       int E, int n_nodes, int nbuck,
                                                       int per_blk) {
    __shared__ int curD[MAX_NB];
    __shared__ int curS[MAX_NB];
    for (int i = threadIdx.x; i < nbuck; i += 256) {
        curD[i] = g_part2[i * NBLK + blockIdx.x];
        curS[i] = g_part2[(nbuck + i) * NBLK + blockIdx.x];
    }
    __syncthreads();
    int start = blockIdx.x * per_blk;
    int end = start + per_blk;
    if (end > E) end = E;
    for (int e = start + threadIdx.x; e < end; e += 256) {
        int s = ei[e];
        int d = ei[E + e];
        if ((unsigned)s >= (unsigned)n_nodes || (unsigned)d >= (unsigned)n_nodes) continue;
        float w0 = (s == d) ? 0.f : w[e];
        int posD = atomicAdd(&curD[d >> CBSH], 1);            // LDS atomic
        g_rec[posD] = make_uint2(((unsigned)s << CBSH) | (unsigned)(d & (CB - 1)),
                                 __float_as_uint(w0));
        int posS = atomicAdd(&curS[s >> CBSH], 1) - E;        // src space is [E,2E)
        g_srec[posS] = make_uint2((unsigned)(s & (CB - 1)), __float_as_uint(w0));
    }
}

// One block per src bucket (256 nodes): LDS f32 accumulate w per local node,
// then write dinv = rsqrt(deg) directly. No global atomics.
__global__ __launch_bounds__(256) void deg_sum_kernel(int E, int n_nodes, int nbuck) {
    __shared__ float ldeg[CB];
    int b = blockIdx.x;
    int rs = g_part2[(nbuck + b) * NBLK] - E;
    int re = g_part2[(nbuck + b + 1) * NBLK] - E;   // b==nbuck-1 hits sentinel (2E)
    ldeg[threadIdx.x] = 0.f;
    __syncthreads();
    for (int i = rs + threadIdx.x; i < re; i += 256) {
        uint2 r = g_srec[i];
        atomicAdd(&ldeg[r.x], __uint_as_float(r.y));   // LDS atomic
    }
    __syncthreads();
    int node = (b << CBSH) + threadIdx.x;
    if (node < n_nodes) {
        float dg = ldeg[threadIdx.x];
        g_deg[node] = (dg > 0.f) ? rsqrtf(dg) : 0.f;
    }
}

// One block per dst bucket (256 nodes, ~4096 records): count local nodes (LDS),
// 4-wave hierarchical exclusive scan -> absolute g_row, then reorder records
// into per-node CSR (g_src2/g_nrm2), computing nrm = -dinv[s]*w*dinv[d] on the
// fly (dinv is 400 KB -> L2-resident; bucket-side dinv staged in LDS).
__global__ __launch_bounds__(256) void fine_sort_kernel(int E, int n_nodes, int nbuck) {
    __shared__ int cnt[CB];
    __shared__ int cur[CB];
    __shared__ float dv[CB];
    __shared__ int wsum[4];
    int b = blockIdx.x;
    int rs = g_part2[b * NBLK];
    int re = g_part2[(b + 1) * NBLK];   // b==nbuck-1 hits first src bin (= E)
    {
        int tid = threadIdx.x;
        cnt[tid] = 0;
        int node = (b << CBSH) + tid;
        dv[tid] = (node < n_nodes) ? g_deg[node] : 0.f;
    }
    __syncthreads();
    for (int i = rs + threadIdx.x; i < re; i += 256)
        atomicAdd(&cnt[g_rec[i].x & (CB - 1)], 1);
    __syncthreads();
    {
        int tid = threadIdx.x;
        int lane = tid & 63;
        int wave = tid >> 6;
        int v = cnt[tid];
        int inc = v;
#pragma unroll
        for (int off = 1; off < 64; off <<= 1) {
            int t = __shfl_up(inc, off, 64);
            if (lane >= off) inc += t;
        }
        if (lane == 63) wsum[wave] = inc;
        __syncthreads();
        int wo = 0;
#pragma unroll
        for (int ww = 0; ww < 4; ++ww) wo += (ww < wave) ? wsum[ww] : 0;
        int start = rs + wo + (inc - v);   // exclusive
        cur[tid] = start;
        int node = (b << CBSH) + tid;
        if (node < n_nodes) g_row[node] = start;
    }
    if (b == nbuck - 1 && threadIdx.x == 0) g_row[n_nodes] = re;
    __syncthreads();
    for (int i = rs + threadIdx.x; i < re; i += 256) {
        uint2 r = g_rec[i];
        int s = (int)(r.x >> CBSH);
        int loc = r.x & (CB - 1);
        float nrm = -g_deg[s] * __uint_as_float(r.y) * dv[loc];
        int pos = atomicAdd(&cur[loc], 1);   // LDS atomic
        g_src2[pos] = s;
        g_nrm2[pos] = nrm;
    }
}

// R4's gather, verbatim: half-wave (32 lanes = 32 features) per node, REGISTER
// accumulator (loads pipeline across iterations), guard-free 4-unroll.
__global__ __launch_bounds__(256) void gather_kernel(const float* __restrict__ x,
                                                     int n_nodes) {
    int t = blockIdx.x * blockDim.x + threadIdx.x;
    int node = t >> 5;
    int f = t & 31;
    if (node >= n_nodes) return;
    int i = g_row[node];
    int end = g_row[node + 1];
    float acc = 0.f;
    for (; i + 4 <= end; i += 4) {
        int   s0 = g_src2[i],     s1 = g_src2[i + 1], s2 = g_src2[i + 2], s3 = g_src2[i + 3];
        float n0 = g_nrm2[i],     n1 = g_nrm2[i + 1], n2 = g_nrm2[i + 2], n3 = g_nrm2[i + 3];
        acc += n0 * x[s0 * FDIM + f] + n1 * x[s1 * FDIM + f]
             + n2 * x[s2 * FDIM + f] + n3 * x[s3 * FDIM + f];
    }
    for (; i < end; ++i) acc += g_nrm2[i] * x[g_src2[i] * FDIM + f];
    g_tx1[node * FDIM + f] = acc;
}

// 64 nodes per 256-thread block. Thread (grp, j) accumulates output feature j
// of gates i,c,o for 8 nodes -> 6 Ws reads per k reused across 8 nodes;
// 24 KB Ws staging amortized over 64 nodes.
__global__ __launch_bounds__(256) void gates64_kernel(
    const float* __restrict__ x,
    const float* __restrict__ Wx, const float* __restrict__ bx,
    const float* __restrict__ bh, const float* __restrict__ wc,
    const float* __restrict__ bg, const float* __restrict__ lin_w,
    const float* __restrict__ lin_b, float* __restrict__ out, int n_nodes) {
    __shared__ float Ws[3 * 2048];      // gates {i,c,o} x K=2 x 32x32 = 24 KB
    __shared__ float xs[GNB * FDIM];    // 8 KB
    __shared__ float ts[GNB * FDIM];    // 8 KB

    for (int idx = threadIdx.x; idx < 2048; idx += 256) {
        Ws[idx]          = Wx[0 * 2048 + idx];
        Ws[2048 + idx]   = Wx[2 * 2048 + idx];
        Ws[4096 + idx]   = Wx[3 * 2048 + idx];
    }
    int node0 = blockIdx.x * GNB;
    for (int t = threadIdx.x; t < GNB * FDIM; t += 256) {
        int n = node0 + (t >> 5);
        int f = t & 31;
        bool ok = (n < n_nodes);
        xs[t] = ok ? x[n * FDIM + f] : 0.f;
        ts[t] = ok ? g_tx1[n * FDIM + f] : 0.f;
    }
    __syncthreads();

    int j   = threadIdx.x & 31;
    int grp = threadIdx.x >> 5;         // 0..7, handles nodes grp*8 .. grp*8+7

    float ai0=0.f,ai1=0.f,ai2=0.f,ai3=0.f,ai4=0.f,ai5=0.f,ai6=0.f,ai7=0.f;
    float ac0=0.f,ac1=0.f,ac2=0.f,ac3=0.f,ac4=0.f,ac5=0.f,ac6=0.f,ac7=0.f;
    float ao0=0.f,ao1=0.f,ao2=0.f,ao3=0.f,ao4=0.f,ao5=0.f,ao6=0.f,ao7=0.f;
    const float* xr = &xs[(grp * 8) * FDIM];
    const float* tr = &ts[(grp * 8) * FDIM];
    for (int k = 0; k < 32; ++k) {
        int o0 = k * 32 + j;
        float wi0 = Ws[o0],        wi1 = Ws[1024 + o0];
        float wc0 = Ws[2048 + o0], wc1 = Ws[3072 + o0];
        float wo0 = Ws[4096 + o0], wo1 = Ws[5120 + o0];
#define GSTEP(m, AI, AC, AO)                                   \
        {   float xv = xr[m * FDIM + k], tv = tr[m * FDIM + k];\
            AI += xv * wi0 + tv * wi1;                         \
            AC += xv * wc0 + tv * wc1;                         \
            AO += xv * wo0 + tv * wo1; }
        GSTEP(0, ai0, ac0, ao0) GSTEP(1, ai1, ac1, ao1)
        GSTEP(2, ai2, ac2, ao2) GSTEP(3, ai3, ac3, ao3)
        GSTEP(4, ai4, ac4, ao4) GSTEP(5, ai5, ac5, ao5)
        GSTEP(6, ai6, ac6, ao6) GSTEP(7, ai7, ac7, ao7)
#undef GSTEP
    }

    float bi = bx[0 * 32 + j] + bh[0 * 32 + j] + bg[0 * 32 + j];
    float bc = bx[2 * 32 + j] + bh[2 * 32 + j] + bg[2 * 32 + j];
    float bo = bx[3 * 32 + j] + bh[3 * 32 + j] + bg[3 * 32 + j];
    float wcp = wc[2 * 32 + j];
    float lwj = lin_w[j];
    float lb0 = lin_b[0];

#define GOUT(m, AI, AC, AO)                                            \
    {   int n = node0 + grp * 8 + m;                                   \
        float I = 1.f / (1.f + __expf(-(AI + bi)));                    \
        float T = tanhf(AC + bc);                                      \
        float C = I * T;                                               \
        float O = 1.f / (1.f + __expf(-(AO + bo + wcp * C)));          \
        float H = O * tanhf(C);                                        \
        float r = fmaxf(H, 0.f) * lwj;                                 \
        _Pragma("unroll")                                              \
        for (int mm = 16; mm > 0; mm >>= 1) r += __shfl_xor(r, mm, 32);\
        if (j == 0 && n < n_nodes) out[n] = r + lb0; }
    GOUT(0, ai0, ac0, ao0) GOUT(1, ai1, ac1, ao1)
    GOUT(2, ai2, ac2, ao2) GOUT(3, ai3, ac3, ao3)
    GOUT(4, ai4, ac4, ao4) GOUT(5, ai5, ac5, ao5)
    GOUT(6, ai6, ac6, ao6) GOUT(7, ai7, ac7, ao7)
#undef GOUT
}

extern "C" void kernel_launch(void* const* d_in, const int* in_sizes, int n_in,
                              void* d_out, int out_size, void* d_ws, size_t ws_size,
                              hipStream_t stream) {
    const float* x     = (const float*)d_in[0];
    const int*   ei    = (const int*)d_in[1];      // int32 on device
    const float* w     = (const float*)d_in[2];
    const float* Wx    = (const float*)d_in[3];
    const float* bx    = (const float*)d_in[4];
    // d_in[5] = Wh: unused (H=0)
    const float* bh    = (const float*)d_in[6];
    const float* wc    = (const float*)d_in[7];
    const float* bg    = (const float*)d_in[8];
    const float* lin_w = (const float*)d_in[9];
    const float* lin_b = (const float*)d_in[10];
    float*       out   = (float*)d_out;

    int n_nodes = in_sizes[0] / FDIM;
    if (n_nodes > MAX_N) n_nodes = MAX_N;
    int E = in_sizes[2];
    if (E > MAX_E) E = MAX_E;

    int nbuck   = (n_nodes + CB - 1) >> CBSH;            // 391 for N=100k
    int per_blk = (E + NBLK - 1) / NBLK;                 // 3125 edges/block
    int n_scan  = 2 * nbuck * NBLK + 1;                  // 400385
    int nb_scan = (n_scan + SCAN_TILE - 1) / SCAN_TILE;  // 196 (<= 1024 for scan2)

    hist2_kernel<<<NBLK, 256, 0, stream>>>(ei, E, n_nodes, nbuck, per_blk);
    scan1_kernel<<<nb_scan, 256, 0, stream>>>(n_scan);
    scan2_kernel<<<1, 256, 0, stream>>>(nb_scan);
    scan3_kernel<<<nb_scan, 256, 0, stream>>>(n_scan);
    scatter2_kernel<<<NBLK, 256, 0, stream>>>(ei, w, E, n_nodes, nbuck, per_blk);
    deg_sum_kernel<<<nbuck, 256, 0, stream>>>(E, n_nodes, nbuck);
    fine_sort_kernel<<<nbuck, 256, 0, stream>>>(E, n_nodes, nbuck);
    {
        long long tot = (long long)n_nodes * 32;
        gather_kernel<<<(int)((tot + 255) / 256), 256, 0, stream>>>(x, n_nodes);
    }
    gates64_kernel<<<(n_nodes + GNB - 1) / GNB, 256, 0, stream>>>(
        x, Wx, bx, bh, wc, bg, lin_w, lin_b, out, n_nodes);
}

// Round 10
// 258.359 us; speedup vs baseline: 2.3664x; 1.0714x over previous
//
#include <hip/hip_runtime.h>

// LSTM-GCN single step from (H=0, C=0).
// Collapsed math: Fg gate dead (C_prev=0), cheb(H,..)=bh, peephole wc[0],wc[1] dead.
//
// R14: R13's bigger buckets didn't fix scatter2's write amplification (WRITE
// 95->85MB, still 3.3x payload) because it is TEMPORAL: each 64B line receives
// its ~8 cursor-ordered stores spread over the kernel's life and L2 evicts the
// line partially-dirty between them (~1 sector flushed per store). Fix:
// scatter_burst -- per block, per phase (dst|src): per-bin counts/bases read
// straight from the scanned matrix (count = part2[flat+1]-part2[flat], no
// histogram recompute), 512-wide LDS scan -> local run bases, one edge pass
// stages records + global positions in LDS, then a coalesced BURST write-out
// (consecutive threads -> consecutive global slots; every line written fully
// in one eviction window). Residual waste = run-boundary sectors only.

#define FDIM 32
#define MAX_N 100000
#define MAX_E 1600000
#define CBSH 8                                // 256 nodes per coarse bucket
#define CB 256
#define MAX_NB ((MAX_N + CB - 1) / CB)        // 391 buckets max
#define NBLK 512                              // blocks in each edge pass
#define SCAN_TILE 2048                        // elements per scan block (256 thr x 8)
#define GNB 64                                // nodes per gates block
#define PERBLK 3136                           // staged records per block (>= 3125)

__device__ float g_deg[MAX_N];                    // dinv (written by deg_sum)
__device__ int   g_part2[2 * MAX_NB * NBLK + 1];  // [dst bins | src bins] counts->offsets
__device__ int   g_blk[1024];                     // scan block sums
__device__ uint2 g_rec[MAX_E];                    // dst-sorted {src<<8|dst_loc, w}
__device__ uint2 g_srec[MAX_E];                   // src-sorted {src_loc, w}
__device__ int   g_row[MAX_N + 1];                // per-node CSR row starts
__device__ int   g_src2[MAX_E];                   // CSR: src per edge, node-sorted
__device__ float g_nrm2[MAX_E];                   // CSR: nrm per edge, node-sorted
__device__ float g_tx1[MAX_N * FDIM];             // L_hat @ x

// One edge pass, NO global atomics: dual LDS histograms of dst>>8 and src>>8,
// flushed non-atomically to g_part2[bin*NBLK + block] (src bins offset by nbuck).
__global__ __launch_bounds__(256) void hist2_kernel(const int* __restrict__ ei,
                                                    int E, int n_nodes, int nbuck,
                                                    int per_blk) {
    __shared__ int hd[MAX_NB];
    __shared__ int hs[MAX_NB];
    for (int i = threadIdx.x; i < nbuck; i += 256) { hd[i] = 0; hs[i] = 0; }
    __syncthreads();
    int start = blockIdx.x * per_blk;
    int end = start + per_blk;
    if (end > E) end = E;
    for (int e = start + threadIdx.x; e < end; e += 256) {
        int s = ei[e];
        int d = ei[E + e];
        if ((unsigned)s >= (unsigned)n_nodes || (unsigned)d >= (unsigned)n_nodes) continue;
        atomicAdd(&hd[d >> CBSH], 1);
        atomicAdd(&hs[s >> CBSH], 1);
    }
    __syncthreads();
    for (int i = threadIdx.x; i < nbuck; i += 256) {
        g_part2[i * NBLK + blockIdx.x] = hd[i];
        g_part2[(nbuck + i) * NBLK + blockIdx.x] = hs[i];
    }
    if (blockIdx.x == 0 && threadIdx.x == 0)
        g_part2[2 * nbuck * NBLK] = 0;        // scan sentinel
}

// --- exclusive scan over g_part2[0..n), 3 kernels, VPT=8 (n ~ 400K) ---
__global__ __launch_bounds__(256) void scan1_kernel(int n) {
    __shared__ int sh[256];
    int tid = threadIdx.x;
    int base = blockIdx.x * SCAN_TILE + tid * 8;
    int v[8];
#pragma unroll
    for (int i = 0; i < 8; ++i) v[i] = (base + i < n) ? g_part2[base + i] : 0;
    int tsum = 0;
#pragma unroll
    for (int i = 0; i < 8; ++i) tsum += v[i];
    sh[tid] = tsum;
    __syncthreads();
    for (int off = 1; off < 256; off <<= 1) {
        int t = (tid >= off) ? sh[tid - off] : 0;
        __syncthreads();
        sh[tid] += t;
        __syncthreads();
    }
    if (tid == 255) g_blk[blockIdx.x] = sh[255];
    int run = sh[tid] - tsum;   // exclusive offset within block
#pragma unroll
    for (int i = 0; i < 8; ++i) {
        if (base + i < n) g_part2[base + i] = run;
        run += v[i];
    }
}

__global__ __launch_bounds__(256) void scan2_kernel(int nb) {   // nb <= 1024
    __shared__ int sh[256];
    int tid = threadIdx.x;
    int base = tid * 4;
    int v[4];
#pragma unroll
    for (int i = 0; i < 4; ++i) v[i] = (base + i < nb) ? g_blk[base + i] : 0;
    int tsum = v[0] + v[1] + v[2] + v[3];
    sh[tid] = tsum;
    __syncthreads();
    for (int off = 1; off < 256; off <<= 1) {
        int t = (tid >= off) ? sh[tid - off] : 0;
        __syncthreads();
        sh[tid] += t;
        __syncthreads();
    }
    int run = sh[tid] - tsum;
#pragma unroll
    for (int i = 0; i < 4; ++i) {
        if (base + i < nb) g_blk[base + i] = run;
        run += v[i];
    }
}

__global__ void scan3_kernel(int n) {
    int off = g_blk[blockIdx.x];
    int base = blockIdx.x * SCAN_TILE + threadIdx.x * 8;
#pragma unroll
    for (int i = 0; i < 8; ++i) {
        int idx = base + i;
        if (idx < n) g_part2[idx] += off;
    }
}

// Two phases (dst records into g_rec, src records into g_srec). Per phase:
// counts/bases from the scanned matrix, 512-wide LDS Hillis-Steele for local
// run bases, cursor-scatter into staged LDS + per-record global position,
// then coalesced burst write-out. No global atomics; lines written fully.
__global__ __launch_bounds__(256) void scatter_burst_kernel(const int* __restrict__ ei,
                                                            const float* __restrict__ w,
                                                            int E, int n_nodes, int nbuck,
                                                            int per_blk) {
    __shared__ int   cnt[512];
    __shared__ int   sc[512];
    __shared__ int   gb[MAX_NB];
    __shared__ int   cur[MAX_NB];
    __shared__ uint2 staged[PERBLK];
    __shared__ int   gpos[PERBLK];
    int tid = threadIdx.x;
    int blk = blockIdx.x;
    int start = blk * per_blk;
    int end = start + per_blk;
    if (end > E) end = E;

    for (int phase = 0; phase < 2; ++phase) {
        cnt[tid] = 0; cnt[tid + 256] = 0;
        __syncthreads();
        for (int i = tid; i < nbuck; i += 256) {
            int flat = (phase * nbuck + i) * NBLK + blk;
            int g0 = g_part2[flat];
            int g1 = g_part2[flat + 1];            // flat successor = run end
            gb[i] = g0 - phase * E;                // src space is [E,2E)
            cnt[i] = g1 - g0;
        }
        __syncthreads();
        sc[tid] = cnt[tid]; sc[tid + 256] = cnt[tid + 256];
        __syncthreads();
        for (int off = 1; off < 512; off <<= 1) {  // inclusive scan, 512 wide
            int v0 = (tid >= off) ? sc[tid - off] : 0;
            int v1 = sc[tid + 256 - off];          // tid+256 >= off always
            __syncthreads();
            sc[tid] += v0; sc[tid + 256] += v1;
            __syncthreads();
        }
        for (int i = tid; i < nbuck; i += 256) cur[i] = sc[i] - cnt[i];
        __syncthreads();
        for (int e = start + tid; e < end; e += 256) {
            int s = ei[e], d = ei[E + e];
            if ((unsigned)s >= (unsigned)n_nodes || (unsigned)d >= (unsigned)n_nodes)
                continue;
            int key = phase ? s : d;
            int bin = key >> CBSH;
            float w0 = (s == d) ? 0.f : w[e];      // self-loops: w=0 both sides
            unsigned pay = phase ? (unsigned)(s & (CB - 1))
                                 : (((unsigned)s << CBSH) | (unsigned)(d & (CB - 1)));
            int p = atomicAdd(&cur[bin], 1);       // LDS cursor
            staged[p] = make_uint2(pay, __float_as_uint(w0));
            gpos[p] = gb[bin] + (p - (sc[bin] - cnt[bin]));
        }
        __syncthreads();
        int tot = sc[511];                         // valid records in this chunk
        if (phase == 0) {
            for (int t = tid; t < tot; t += 256) g_rec[gpos[t]] = staged[t];
        } else {
            for (int t = tid; t < tot; t += 256) g_srec[gpos[t]] = staged[t];
        }
        __syncthreads();
    }
}

// One block per src bucket (256 nodes): LDS f32 accumulate w per local node,
// then write dinv = rsqrt(deg) directly. No global atomics.
__global__ __launch_bounds__(256) void deg_sum_kernel(int E, int n_nodes, int nbuck) {
    __shared__ float ldeg[CB];
    int b = blockIdx.x;
    int rs = g_part2[(nbuck + b) * NBLK] - E;
    int re = g_part2[(nbuck + b + 1) * NBLK] - E;   // b==nbuck-1 hits sentinel (2E)
    ldeg[threadIdx.x] = 0.f;
    __syncthreads();
    for (int i = rs + threadIdx.x; i < re; i += 256) {
        uint2 r = g_srec[i];
        atomicAdd(&ldeg[r.x], __uint_as_float(r.y));   // LDS atomic
    }
    __syncthreads();
    int node = (b << CBSH) + threadIdx.x;
    if (node < n_nodes) {
        float dg = ldeg[threadIdx.x];
        g_deg[node] = (dg > 0.f) ? rsqrtf(dg) : 0.f;
    }
}

// One block per dst bucket (256 nodes, ~4096 records): count local nodes (LDS),
// 4-wave hierarchical exclusive scan -> absolute g_row, then reorder records
// into per-node CSR (g_src2/g_nrm2), computing nrm = -dinv[s]*w*dinv[d] on the
// fly (dinv is 400 KB -> L2-resident; bucket-side dinv staged in LDS).
__global__ __launch_bounds__(256) void fine_sort_kernel(int E, int n_nodes, int nbuck) {
    __shared__ int cnt[CB];
    __shared__ int cur[CB];
    __shared__ float dv[CB];
    __shared__ int wsum[4];
    int b = blockIdx.x;
    int rs = g_part2[b * NBLK];
    int re = g_part2[(b + 1) * NBLK];   // b==nbuck-1 hits first src bin (= E)
    {
        int tid = threadIdx.x;
        cnt[tid] = 0;
        int node = (b << CBSH) + tid;
        dv[tid] = (node < n_nodes) ? g_deg[node] : 0.f;
    }
    __syncthreads();
    for (int i = rs + threadIdx.x; i < re; i += 256)
        atomicAdd(&cnt[g_rec[i].x & (CB - 1)], 1);
    __syncthreads();
    {
        int tid = threadIdx.x;
        int lane = tid & 63;
        int wave = tid >> 6;
        int v = cnt[tid];
        int inc = v;
#pragma unroll
        for (int off = 1; off < 64; off <<= 1) {
            int t = __shfl_up(inc, off, 64);
            if (lane >= off) inc += t;
        }
        if (lane == 63) wsum[wave] = inc;
        __syncthreads();
        int wo = 0;
#pragma unroll
        for (int ww = 0; ww < 4; ++ww) wo += (ww < wave) ? wsum[ww] : 0;
        int start = rs + wo + (inc - v);   // exclusive
        cur[tid] = start;
        int node = (b << CBSH) + tid;
        if (node < n_nodes) g_row[node] = start;
    }
    if (b == nbuck - 1 && threadIdx.x == 0) g_row[n_nodes] = re;
    __syncthreads();
    for (int i = rs + threadIdx.x; i < re; i += 256) {
        uint2 r = g_rec[i];
        int s = (int)(r.x >> CBSH);
        int loc = r.x & (CB - 1);
        float nrm = -g_deg[s] * __uint_as_float(r.y) * dv[loc];
        int pos = atomicAdd(&cur[loc], 1);   // LDS atomic
        g_src2[pos] = s;
        g_nrm2[pos] = nrm;
    }
}

// R4's gather, verbatim: half-wave (32 lanes = 32 features) per node, REGISTER
// accumulator (loads pipeline across iterations), guard-free 4-unroll.
__global__ __launch_bounds__(256) void gather_kernel(const float* __restrict__ x,
                                                     int n_nodes) {
    int t = blockIdx.x * blockDim.x + threadIdx.x;
    int node = t >> 5;
    int f = t & 31;
    if (node >= n_nodes) return;
    int i = g_row[node];
    int end = g_row[node + 1];
    float acc = 0.f;
    for (; i + 4 <= end; i += 4) {
        int   s0 = g_src2[i],     s1 = g_src2[i + 1], s2 = g_src2[i + 2], s3 = g_src2[i + 3];
        float n0 = g_nrm2[i],     n1 = g_nrm2[i + 1], n2 = g_nrm2[i + 2], n3 = g_nrm2[i + 3];
        acc += n0 * x[s0 * FDIM + f] + n1 * x[s1 * FDIM + f]
             + n2 * x[s2 * FDIM + f] + n3 * x[s3 * FDIM + f];
    }
    for (; i < end; ++i) acc += g_nrm2[i] * x[g_src2[i] * FDIM + f];
    g_tx1[node * FDIM + f] = acc;
}

// 64 nodes per 256-thread block. Thread (grp, j) accumulates output feature j
// of gates i,c,o for 8 nodes -> 6 Ws reads per k reused across 8 nodes;
// 24 KB Ws staging amortized over 64 nodes.
__global__ __launch_bounds__(256) void gates64_kernel(
    const float* __restrict__ x,
    const float* __restrict__ Wx, const float* __restrict__ bx,
    const float* __restrict__ bh, const float* __restrict__ wc,
    const float* __restrict__ bg, const float* __restrict__ lin_w,
    const float* __restrict__ lin_b, float* __restrict__ out, int n_nodes) {
    __shared__ float Ws[3 * 2048];      // gates {i,c,o} x K=2 x 32x32 = 24 KB
    __shared__ float xs[GNB * FDIM];    // 8 KB
    __shared__ float ts[GNB * FDIM];    // 8 KB

    for (int idx = threadIdx.x; idx < 2048; idx += 256) {
        Ws[idx]          = Wx[0 * 2048 + idx];
        Ws[2048 + idx]   = Wx[2 * 2048 + idx];
        Ws[4096 + idx]   = Wx[3 * 2048 + idx];
    }
    int node0 = blockIdx.x * GNB;
    for (int t = threadIdx.x; t < GNB * FDIM; t += 256) {
        int n = node0 + (t >> 5);
        int f = t & 31;
        bool ok = (n < n_nodes);
        xs[t] = ok ? x[n * FDIM + f] : 0.f;
        ts[t] = ok ? g_tx1[n * FDIM + f] : 0.f;
    }
    __syncthreads();

    int j   = threadIdx.x & 31;
    int grp = threadIdx.x >> 5;         // 0..7, handles nodes grp*8 .. grp*8+7

    float ai0=0.f,ai1=0.f,ai2=0.f,ai3=0.f,ai4=0.f,ai5=0.f,ai6=0.f,ai7=0.f;
    float ac0=0.f,ac1=0.f,ac2=0.f,ac3=0.f,ac4=0.f,ac5=0.f,ac6=0.f,ac7=0.f;
    float ao0=0.f,ao1=0.f,ao2=0.f,ao3=0.f,ao4=0.f,ao5=0.f,ao6=0.f,ao7=0.f;
    const float* xr = &xs[(grp * 8) * FDIM];
    const float* tr = &ts[(grp * 8) * FDIM];
    for (int k = 0; k < 32; ++k) {
        int o0 = k * 32 + j;
        float wi0 = Ws[o0],        wi1 = Ws[1024 + o0];
        float wc0 = Ws[2048 + o0], wc1 = Ws[3072 + o0];
        float wo0 = Ws[4096 + o0], wo1 = Ws[5120 + o0];
#define GSTEP(m, AI, AC, AO)                                   \
        {   float xv = xr[m * FDIM + k], tv = tr[m * FDIM + k];\
            AI += xv * wi0 + tv * wi1;                         \
            AC += xv * wc0 + tv * wc1;                         \
            AO += xv * wo0 + tv * wo1; }
        GSTEP(0, ai0, ac0, ao0) GSTEP(1, ai1, ac1, ao1)
        GSTEP(2, ai2, ac2, ao2) GSTEP(3, ai3, ac3, ao3)
        GSTEP(4, ai4, ac4, ao4) GSTEP(5, ai5, ac5, ao5)
        GSTEP(6, ai6, ac6, ao6) GSTEP(7, ai7, ac7, ao7)
#undef GSTEP
    }

    float bi = bx[0 * 32 + j] + bh[0 * 32 + j] + bg[0 * 32 + j];
    float bc = bx[2 * 32 + j] + bh[2 * 32 + j] + bg[2 * 32 + j];
    float bo = bx[3 * 32 + j] + bh[3 * 32 + j] + bg[3 * 32 + j];
    float wcp = wc[2 * 32 + j];
    float lwj = lin_w[j];
    float lb0 = lin_b[0];

#define GOUT(m, AI, AC, AO)                                            \
    {   int n = node0 + grp * 8 + m;                                   \
        float I = 1.f / (1.f + __expf(-(AI + bi)));                    \
        float T = tanhf(AC + bc);                                      \
        float C = I * T;                                               \
        float O = 1.f / (1.f + __expf(-(AO + bo + wcp * C)));          \
        float H = O * tanhf(C);                                        \
        float r = fmaxf(H, 0.f) * lwj;                                 \
        _Pragma("unroll")                                              \
        for (int mm = 16; mm > 0; mm >>= 1) r += __shfl_xor(r, mm, 32);\
        if (j == 0 && n < n_nodes) out[n] = r + lb0; }
    GOUT(0, ai0, ac0, ao0) GOUT(1, ai1, ac1, ao1)
    GOUT(2, ai2, ac2, ao2) GOUT(3, ai3, ac3, ao3)
    GOUT(4, ai4, ac4, ao4) GOUT(5, ai5, ac5, ao5)
    GOUT(6, ai6, ac6, ao6) GOUT(7, ai7, ac7, ao7)
#undef GOUT
}

extern "C" void kernel_launch(void* const* d_in, const int* in_sizes, int n_in,
                              void* d_out, int out_size, void* d_ws, size_t ws_size,
                              hipStream_t stream) {
    const float* x     = (const float*)d_in[0];
    const int*   ei    = (const int*)d_in[1];      // int32 on device
    const float* w     = (const float*)d_in[2];
    const float* Wx    = (const float*)d_in[3];
    const float* bx    = (const float*)d_in[4];
    // d_in[5] = Wh: unused (H=0)
    const float* bh    = (const float*)d_in[6];
    const float* wc    = (const float*)d_in[7];
    const float* bg    = (const float*)d_in[8];
    const float* lin_w = (const float*)d_in[9];
    const float* lin_b = (const float*)d_in[10];
    float*       out   = (float*)d_out;

    int n_nodes = in_sizes[0] / FDIM;
    if (n_nodes > MAX_N) n_nodes = MAX_N;
    int E = in_sizes[2];
    if (E > MAX_E) E = MAX_E;

    int nbuck   = (n_nodes + CB - 1) >> CBSH;            // 391 for N=100k
    int per_blk = (E + NBLK - 1) / NBLK;                 // 3125 edges/block
    int n_scan  = 2 * nbuck * NBLK + 1;                  // 400385
    int nb_scan = (n_scan + SCAN_TILE - 1) / SCAN_TILE;  // 196 (<= 1024 for scan2)

    hist2_kernel<<<NBLK, 256, 0, stream>>>(ei, E, n_nodes, nbuck, per_blk);
    scan1_kernel<<<nb_scan, 256, 0, stream>>>(n_scan);
    scan2_kernel<<<1, 256, 0, stream>>>(nb_scan);
    scan3_kernel<<<nb_scan, 256, 0, stream>>>(n_scan);
    scatter_burst_kernel<<<NBLK, 256, 0, stream>>>(ei, w, E, n_nodes, nbuck, per_blk);
    deg_sum_kernel<<<nbuck, 256, 0, stream>>>(E, n_nodes, nbuck);
    fine_sort_kernel<<<nbuck, 256, 0, stream>>>(E, n_nodes, nbuck);
    {
        long long tot = (long long)n_nodes * 32;
        gather_kernel<<<(int)((tot + 255) / 256), 256, 0, stream>>>(x, n_nodes);
    }
    gates64_kernel<<<(n_nodes + GNB - 1) / GNB, 256, 0, stream>>>(
        x, Wx, bx, bh, wc, bg, lin_w, lin_b, out, n_nodes);
}

// Round 11
// 255.891 us; speedup vs baseline: 2.3893x; 1.0096x over previous
//
#include <hip/hip_runtime.h>

// LSTM-GCN single step from (H=0, C=0).
// Collapsed math: Fg gate dead (C_prev=0), cheb(H,..)=bh, peephole wc[0],wc[1] dead.
//
// R15: R14's burst-write fixed the sort (258 us). Top dispatch now gates64
// (50.6 us, VALUBusy 57%, LDS-issue-bound: 22 scalar ds_read per k vs 48 FMA).
// Fix: k processed in chunks of 4 -- x/t read as float4 broadcasts (b128,
// conflict-free), weights stay b32 coalesced -> ds instr 704->~320/thread;
// launch_bounds(256,4) pins VGPR<=128 to keep 4 blocks/CU at 40KB LDS.
// Also int4/float4 edge reads in hist2/scatter_burst (per-block ranges rounded
// to x4) and int4/float4 CSR reads in gather (peel to 16B alignment).

#define FDIM 32
#define MAX_N 100000
#define MAX_E 1600000
#define CBSH 8                                // 256 nodes per coarse bucket
#define CB 256
#define MAX_NB ((MAX_N + CB - 1) / CB)        // 391 buckets max
#define NBLK 512                              // blocks in each edge pass
#define SCAN_TILE 2048                        // elements per scan block (256 thr x 8)
#define GNB 64                                // nodes per gates block
#define PERBLK 3136                           // staged records per block (>= 3128)

__device__ float g_deg[MAX_N];                    // dinv (written by deg_sum)
__device__ int   g_part2[2 * MAX_NB * NBLK + 1];  // [dst bins | src bins] counts->offsets
__device__ int   g_blk[1024];                     // scan block sums
__device__ uint2 g_rec[MAX_E];                    // dst-sorted {src<<8|dst_loc, w}
__device__ uint2 g_srec[MAX_E];                   // src-sorted {src_loc, w}
__device__ int   g_row[MAX_N + 1];                // per-node CSR row starts
__device__ int   g_src2[MAX_E];                   // CSR: src per edge, node-sorted
__device__ float g_nrm2[MAX_E];                   // CSR: nrm per edge, node-sorted
__device__ float g_tx1[MAX_N * FDIM];             // L_hat @ x

// One edge pass, NO global atomics: dual LDS histograms of dst>>8 and src>>8,
// flushed non-atomically to g_part2[bin*NBLK + block]. Edge reads int4.
__global__ __launch_bounds__(256) void hist2_kernel(const int* __restrict__ ei,
                                                    int E, int n_nodes, int nbuck,
                                                    int per_blk) {
    __shared__ int hd[MAX_NB];
    __shared__ int hs[MAX_NB];
    for (int i = threadIdx.x; i < nbuck; i += 256) { hd[i] = 0; hs[i] = 0; }
    __syncthreads();
    int start = blockIdx.x * per_blk;            // per_blk % 4 == 0 -> aligned
    int end = start + per_blk;
    if (end > E) end = E;
    for (int base = start; base < end; base += 1024) {
        int e = base + threadIdx.x * 4;
        if (e + 4 <= end) {
            int4 s4 = *(const int4*)(ei + e);
            int4 d4 = *(const int4*)(ei + E + e);
#define H2(S, D) if ((unsigned)(S) < (unsigned)n_nodes && (unsigned)(D) < (unsigned)n_nodes) { \
                atomicAdd(&hd[(D) >> CBSH], 1); atomicAdd(&hs[(S) >> CBSH], 1); }
            H2(s4.x, d4.x) H2(s4.y, d4.y) H2(s4.z, d4.z) H2(s4.w, d4.w)
#undef H2
        } else if (e < end) {
            for (int q = e; q < end; ++q) {
                int s = ei[q], d = ei[E + q];
                if ((unsigned)s >= (unsigned)n_nodes || (unsigned)d >= (unsigned)n_nodes)
                    continue;
                atomicAdd(&hd[d >> CBSH], 1);
                atomicAdd(&hs[s >> CBSH], 1);
            }
        }
    }
    __syncthreads();
    for (int i = threadIdx.x; i < nbuck; i += 256) {
        g_part2[i * NBLK + blockIdx.x] = hd[i];
        g_part2[(nbuck + i) * NBLK + blockIdx.x] = hs[i];
    }
    if (blockIdx.x == 0 && threadIdx.x == 0)
        g_part2[2 * nbuck * NBLK] = 0;        // scan sentinel
}

// --- exclusive scan over g_part2[0..n), 3 kernels, VPT=8 (n ~ 400K) ---
__global__ __launch_bounds__(256) void scan1_kernel(int n) {
    __shared__ int sh[256];
    int tid = threadIdx.x;
    int base = blockIdx.x * SCAN_TILE + tid * 8;
    int v[8];
#pragma unroll
    for (int i = 0; i < 8; ++i) v[i] = (base + i < n) ? g_part2[base + i] : 0;
    int tsum = 0;
#pragma unroll
    for (int i = 0; i < 8; ++i) tsum += v[i];
    sh[tid] = tsum;
    __syncthreads();
    for (int off = 1; off < 256; off <<= 1) {
        int t = (tid >= off) ? sh[tid - off] : 0;
        __syncthreads();
        sh[tid] += t;
        __syncthreads();
    }
    if (tid == 255) g_blk[blockIdx.x] = sh[255];
    int run = sh[tid] - tsum;   // exclusive offset within block
#pragma unroll
    for (int i = 0; i < 8; ++i) {
        if (base + i < n) g_part2[base + i] = run;
        run += v[i];
    }
}

__global__ __launch_bounds__(256) void scan2_kernel(int nb) {   // nb <= 1024
    __shared__ int sh[256];
    int tid = threadIdx.x;
    int base = tid * 4;
    int v[4];
#pragma unroll
    for (int i = 0; i < 4; ++i) v[i] = (base + i < nb) ? g_blk[base + i] : 0;
    int tsum = v[0] + v[1] + v[2] + v[3];
    sh[tid] = tsum;
    __syncthreads();
    for (int off = 1; off < 256; off <<= 1) {
        int t = (tid >= off) ? sh[tid - off] : 0;
        __syncthreads();
        sh[tid] += t;
        __syncthreads();
    }
    int run = sh[tid] - tsum;
#pragma unroll
    for (int i = 0; i < 4; ++i) {
        if (base + i < nb) g_blk[base + i] = run;
        run += v[i];
    }
}

__global__ void scan3_kernel(int n) {
    int off = g_blk[blockIdx.x];
    int base = blockIdx.x * SCAN_TILE + threadIdx.x * 8;
#pragma unroll
    for (int i = 0; i < 8; ++i) {
        int idx = base + i;
        if (idx < n) g_part2[idx] += off;
    }
}

// Two phases (dst records into g_rec, src records into g_srec). Per phase:
// counts/bases from the scanned matrix, 512-wide LDS Hillis-Steele for local
// run bases, cursor-scatter into staged LDS + per-record global position,
// then coalesced burst write-out. Edge reads int4/float4.
__global__ __launch_bounds__(256) void scatter_burst_kernel(const int* __restrict__ ei,
                                                            const float* __restrict__ w,
                                                            int E, int n_nodes, int nbuck,
                                                            int per_blk) {
    __shared__ int   cnt[512];
    __shared__ int   sc[512];
    __shared__ int   gb[MAX_NB];
    __shared__ int   cur[MAX_NB];
    __shared__ uint2 staged[PERBLK];
    __shared__ int   gpos[PERBLK];
    int tid = threadIdx.x;
    int blk = blockIdx.x;
    int start = blk * per_blk;
    int end = start + per_blk;
    if (end > E) end = E;

    for (int phase = 0; phase < 2; ++phase) {
        cnt[tid] = 0; cnt[tid + 256] = 0;
        __syncthreads();
        for (int i = tid; i < nbuck; i += 256) {
            int flat = (phase * nbuck + i) * NBLK + blk;
            int g0 = g_part2[flat];
            int g1 = g_part2[flat + 1];            // flat successor = run end
            gb[i] = g0 - phase * E;                // src space is [E,2E)
            cnt[i] = g1 - g0;
        }
        __syncthreads();
        sc[tid] = cnt[tid]; sc[tid + 256] = cnt[tid + 256];
        __syncthreads();
        for (int off = 1; off < 512; off <<= 1) {  // inclusive scan, 512 wide
            int v0 = (tid >= off) ? sc[tid - off] : 0;
            int v1 = sc[tid + 256 - off];          // tid+256 >= off always
            __syncthreads();
            sc[tid] += v0; sc[tid + 256] += v1;
            __syncthreads();
        }
        for (int i = tid; i < nbuck; i += 256) cur[i] = sc[i] - cnt[i];
        __syncthreads();
#define SB1(S, D, W)                                                            \
        {   int s = (S), d = (D);                                               \
            if ((unsigned)s < (unsigned)n_nodes && (unsigned)d < (unsigned)n_nodes) { \
                int key = phase ? s : d;                                        \
                int bin = key >> CBSH;                                          \
                float w0 = (s == d) ? 0.f : (W);                                \
                unsigned pay = phase ? (unsigned)(s & (CB - 1))                 \
                    : (((unsigned)s << CBSH) | (unsigned)(d & (CB - 1)));       \
                int p = atomicAdd(&cur[bin], 1);                                \
                staged[p] = make_uint2(pay, __float_as_uint(w0));               \
                gpos[p] = gb[bin] + (p - (sc[bin] - cnt[bin]));                 \
            } }
        for (int base = start; base < end; base += 1024) {
            int e = base + tid * 4;
            if (e + 4 <= end) {
                int4   s4 = *(const int4*)(ei + e);
                int4   d4 = *(const int4*)(ei + E + e);
                float4 w4 = *(const float4*)(w + e);
                SB1(s4.x, d4.x, w4.x) SB1(s4.y, d4.y, w4.y)
                SB1(s4.z, d4.z, w4.z) SB1(s4.w, d4.w, w4.w)
            } else if (e < end) {
                for (int q = e; q < end; ++q) SB1(ei[q], ei[E + q], w[q])
            }
        }
#undef SB1
        __syncthreads();
        int tot = sc[511];                         // valid records in this chunk
        if (phase == 0) {
            for (int t = tid; t < tot; t += 256) g_rec[gpos[t]] = staged[t];
        } else {
            for (int t = tid; t < tot; t += 256) g_srec[gpos[t]] = staged[t];
        }
        __syncthreads();
    }
}

// One block per src bucket (256 nodes): LDS f32 accumulate w per local node,
// then write dinv = rsqrt(deg) directly. No global atomics.
__global__ __launch_bounds__(256) void deg_sum_kernel(int E, int n_nodes, int nbuck) {
    __shared__ float ldeg[CB];
    int b = blockIdx.x;
    int rs = g_part2[(nbuck + b) * NBLK] - E;
    int re = g_part2[(nbuck + b + 1) * NBLK] - E;   // b==nbuck-1 hits sentinel (2E)
    ldeg[threadIdx.x] = 0.f;
    __syncthreads();
    for (int i = rs + threadIdx.x; i < re; i += 256) {
        uint2 r = g_srec[i];
        atomicAdd(&ldeg[r.x], __uint_as_float(r.y));   // LDS atomic
    }
    __syncthreads();
    int node = (b << CBSH) + threadIdx.x;
    if (node < n_nodes) {
        float dg = ldeg[threadIdx.x];
        g_deg[node] = (dg > 0.f) ? rsqrtf(dg) : 0.f;
    }
}

// One block per dst bucket (256 nodes, ~4096 records): count local nodes (LDS),
// 4-wave hierarchical exclusive scan -> absolute g_row, then reorder records
// into per-node CSR (g_src2/g_nrm2), computing nrm = -dinv[s]*w*dinv[d] on the
// fly (dinv is 400 KB -> L2-resident; bucket-side dinv staged in LDS).
__global__ __launch_bounds__(256) void fine_sort_kernel(int E, int n_nodes, int nbuck) {
    __shared__ int cnt[CB];
    __shared__ int cur[CB];
    __shared__ float dv[CB];
    __shared__ int wsum[4];
    int b = blockIdx.x;
    int rs = g_part2[b * NBLK];
    int re = g_part2[(b + 1) * NBLK];   // b==nbuck-1 hits first src bin (= E)
    {
        int tid = threadIdx.x;
        cnt[tid] = 0;
        int node = (b << CBSH) + tid;
        dv[tid] = (node < n_nodes) ? g_deg[node] : 0.f;
    }
    __syncthreads();
    for (int i = rs + threadIdx.x; i < re; i += 256)
        atomicAdd(&cnt[g_rec[i].x & (CB - 1)], 1);
    __syncthreads();
    {
        int tid = threadIdx.x;
        int lane = tid & 63;
        int wave = tid >> 6;
        int v = cnt[tid];
        int inc = v;
#pragma unroll
        for (int off = 1; off < 64; off <<= 1) {
            int t = __shfl_up(inc, off, 64);
            if (lane >= off) inc += t;
        }
        if (lane == 63) wsum[wave] = inc;
        __syncthreads();
        int wo = 0;
#pragma unroll
        for (int ww = 0; ww < 4; ++ww) wo += (ww < wave) ? wsum[ww] : 0;
        int start = rs + wo + (inc - v);   // exclusive
        cur[tid] = start;
        int node = (b << CBSH) + tid;
        if (node < n_nodes) g_row[node] = start;
    }
    if (b == nbuck - 1 && threadIdx.x == 0) g_row[n_nodes] = re;
    __syncthreads();
    for (int i = rs + threadIdx.x; i < re; i += 256) {
        uint2 r = g_rec[i];
        int s = (int)(r.x >> CBSH);
        int loc = r.x & (CB - 1);
        float nrm = -g_deg[s] * __uint_as_float(r.y) * dv[loc];
        int pos = atomicAdd(&cur[loc], 1);   // LDS atomic
        g_src2[pos] = s;
        g_nrm2[pos] = nrm;
    }
}

// Half-wave (32 lanes = 32 features) per node, REGISTER accumulator, CSR reads
// vectorized int4/float4 after a peel to 16B alignment (i uniform per half-wave).
__global__ __launch_bounds__(256) void gather_kernel(const float* __restrict__ x,
                                                     int n_nodes) {
    int t = blockIdx.x * blockDim.x + threadIdx.x;
    int node = t >> 5;
    int f = t & 31;
    if (node >= n_nodes) return;
    int i = g_row[node];
    int end = g_row[node + 1];
    float acc = 0.f;
    while (i < end && (i & 3)) {           // peel to 16B alignment
        acc += g_nrm2[i] * x[g_src2[i] * FDIM + f];
        ++i;
    }
    for (; i + 4 <= end; i += 4) {
        int4   s4 = *(const int4*)(g_src2 + i);
        float4 n4 = *(const float4*)(g_nrm2 + i);
        acc += n4.x * x[s4.x * FDIM + f] + n4.y * x[s4.y * FDIM + f]
             + n4.z * x[s4.z * FDIM + f] + n4.w * x[s4.w * FDIM + f];
    }
    for (; i < end; ++i) acc += g_nrm2[i] * x[g_src2[i] * FDIM + f];
    g_tx1[node * FDIM + f] = acc;
}

// 64 nodes per 256-thread block. Thread (grp, j) accumulates output feature j
// of gates i,c,o for 8 nodes. k processed in chunks of 4: x/t read as float4
// broadcasts (b128, conflict-free), weights b32 coalesced -> ds instructions
// per thread 704 -> ~320. launch_bounds(256,4) pins VGPR<=128 for 4 blocks/CU.
__global__ __launch_bounds__(256, 4) void gates64_kernel(
    const float* __restrict__ x,
    const float* __restrict__ Wx, const float* __restrict__ bx,
    const float* __restrict__ bh, const float* __restrict__ wc,
    const float* __restrict__ bg, const float* __restrict__ lin_w,
    const float* __restrict__ lin_b, float* __restrict__ out, int n_nodes) {
    __shared__ float Ws[3 * 2048];      // gates {i,c,o} x K=2 x 32x32 = 24 KB
    __shared__ float xs[GNB * FDIM];    // 8 KB
    __shared__ float ts[GNB * FDIM];    // 8 KB

    for (int idx = threadIdx.x; idx < 512; idx += 256) {
        *(float4*)&Ws[idx * 4]        = *(const float4*)&Wx[0 * 2048 + idx * 4];
        *(float4*)&Ws[2048 + idx * 4] = *(const float4*)&Wx[2 * 2048 + idx * 4];
        *(float4*)&Ws[4096 + idx * 4] = *(const float4*)&Wx[3 * 2048 + idx * 4];
    }
    int node0 = blockIdx.x * GNB;
    for (int t = threadIdx.x; t < GNB * FDIM / 4; t += 256) {
        int q = t * 4;
        int n = node0 + (q >> 5);
        float4 xv = make_float4(0.f, 0.f, 0.f, 0.f);
        float4 tv = make_float4(0.f, 0.f, 0.f, 0.f);
        if (n < n_nodes) {
            xv = *(const float4*)&x[n * FDIM + (q & 31)];
            tv = *(const float4*)&g_tx1[n * FDIM + (q & 31)];
        }
        *(float4*)&xs[q] = xv;
        *(float4*)&ts[q] = tv;
    }
    __syncthreads();

    int j   = threadIdx.x & 31;
    int grp = threadIdx.x >> 5;         // 0..7, handles nodes grp*8 .. grp*8+7

    float ai0=0.f,ai1=0.f,ai2=0.f,ai3=0.f,ai4=0.f,ai5=0.f,ai6=0.f,ai7=0.f;
    float ac0=0.f,ac1=0.f,ac2=0.f,ac3=0.f,ac4=0.f,ac5=0.f,ac6=0.f,ac7=0.f;
    float ao0=0.f,ao1=0.f,ao2=0.f,ao3=0.f,ao4=0.f,ao5=0.f,ao6=0.f,ao7=0.f;
    const float* xr = &xs[(grp * 8) * FDIM];
    const float* tr = &ts[(grp * 8) * FDIM];
    for (int k4 = 0; k4 < 32; k4 += 4) {
        float4 xv0 = *(const float4*)(xr + 0 * FDIM + k4);
        float4 xv1 = *(const float4*)(xr + 1 * FDIM + k4);
        float4 xv2 = *(const float4*)(xr + 2 * FDIM + k4);
        float4 xv3 = *(const float4*)(xr + 3 * FDIM + k4);
        float4 xv4 = *(const float4*)(xr + 4 * FDIM + k4);
        float4 xv5 = *(const float4*)(xr + 5 * FDIM + k4);
        float4 xv6 = *(const float4*)(xr + 6 * FDIM + k4);
        float4 xv7 = *(const float4*)(xr + 7 * FDIM + k4);
        float4 tv0 = *(const float4*)(tr + 0 * FDIM + k4);
        float4 tv1 = *(const float4*)(tr + 1 * FDIM + k4);
        float4 tv2 = *(const float4*)(tr + 2 * FDIM + k4);
        float4 tv3 = *(const float4*)(tr + 3 * FDIM + k4);
        float4 tv4 = *(const float4*)(tr + 4 * FDIM + k4);
        float4 tv5 = *(const float4*)(tr + 5 * FDIM + k4);
        float4 tv6 = *(const float4*)(tr + 6 * FDIM + k4);
        float4 tv7 = *(const float4*)(tr + 7 * FDIM + k4);
#define KSTEP(kc, COMP)                                        \
        {   int o0 = (k4 + kc) * 32 + j;                       \
            float wi0 = Ws[o0],        wi1 = Ws[1024 + o0];    \
            float wg0 = Ws[2048 + o0], wg1 = Ws[3072 + o0];    \
            float wo0 = Ws[4096 + o0], wo1 = Ws[5120 + o0];    \
            ai0 += xv0.COMP * wi0 + tv0.COMP * wi1;            \
            ac0 += xv0.COMP * wg0 + tv0.COMP * wg1;            \
            ao0 += xv0.COMP * wo0 + tv0.COMP * wo1;            \
            ai1 += xv1.COMP * wi0 + tv1.COMP * wi1;            \
            ac1 += xv1.COMP * wg0 + tv1.COMP * wg1;            \
            ao1 += xv1.COMP * wo0 + tv1.COMP * wo1;            \
            ai2 += xv2.COMP * wi0 + tv2.COMP * wi1;            \
            ac2 += xv2.COMP * wg0 + tv2.COMP * wg1;            \
            ao2 += xv2.COMP * wo0 + tv2.COMP * wo1;            \
            ai3 += xv3.COMP * wi0 + tv3.COMP * wi1;            \
            ac3 += xv3.COMP * wg0 + tv3.COMP * wg1;            \
            ao3 += xv3.COMP * wo0 + tv3.COMP * wo1;            \
            ai4 += xv4.COMP * wi0 + tv4.COMP * wi1;            \
            ac4 += xv4.COMP * wg0 + tv4.COMP * wg1;            \
            ao4 += xv4.COMP * wo0 + tv4.COMP * wo1;            \
            ai5 += xv5.COMP * wi0 + tv5.COMP * wi1;            \
            ac5 += xv5.COMP * wg0 + tv5.COMP * wg1;            \
            ao5 += xv5.COMP * wo0 + tv5.COMP * wo1;            \
            ai6 += xv6.COMP * wi0 + tv6.COMP * wi1;            \
            ac6 += xv6.COMP * wg0 + tv6.COMP * wg1;            \
            ao6 += xv6.COMP * wo0 + tv6.COMP * wo1;            \
            ai7 += xv7.COMP * wi0 + tv7.COMP * wi1;            \
            ac7 += xv7.COMP * wg0 + tv7.COMP * wg1;            \
            ao7 += xv7.COMP * wo0 + tv7.COMP * wo1;            \
        }
        KSTEP(0, x) KSTEP(1, y) KSTEP(2, z) KSTEP(3, w)
#undef KSTEP
    }

    float bi = bx[0 * 32 + j] + bh[0 * 32 + j] + bg[0 * 32 + j];
    float bc = bx[2 * 32 + j] + bh[2 * 32 + j] + bg[2 * 32 + j];
    float bo = bx[3 * 32 + j] + bh[3 * 32 + j] + bg[3 * 32 + j];
    float wcp = wc[2 * 32 + j];
    float lwj = lin_w[j];
    float lb0 = lin_b[0];

#define GOUT(m, AI, AC, AO)                                            \
    {   int n = node0 + grp * 8 + m;                                   \
        float I = 1.f / (1.f + __expf(-(AI + bi)));                    \
        float T = tanhf(AC + bc);                                      \
        float C = I * T;                                               \
        float O = 1.f / (1.f + __expf(-(AO + bo + wcp * C)));          \
        float H = O * tanhf(C);                                        \
        float r = fmaxf(H, 0.f) * lwj;                                 \
        _Pragma("unroll")                                              \
        for (int mm = 16; mm > 0; mm >>= 1) r += __shfl_xor(r, mm, 32);\
        if (j == 0 && n < n_nodes) out[n] = r + lb0; }
    GOUT(0, ai0, ac0, ao0) GOUT(1, ai1, ac1, ao1)
    GOUT(2, ai2, ac2, ao2) GOUT(3, ai3, ac3, ao3)
    GOUT(4, ai4, ac4, ao4) GOUT(5, ai5, ac5, ao5)
    GOUT(6, ai6, ac6, ao6) GOUT(7, ai7, ac7, ao7)
#undef GOUT
}

extern "C" void kernel_launch(void* const* d_in, const int* in_sizes, int n_in,
                              void* d_out, int out_size, void* d_ws, size_t ws_size,
                              hipStream_t stream) {
    const float* x     = (const float*)d_in[0];
    const int*   ei    = (const int*)d_in[1];      // int32 on device
    const float* w     = (const float*)d_in[2];
    const float* Wx    = (const float*)d_in[3];
    const float* bx    = (const float*)d_in[4];
    // d_in[5] = Wh: unused (H=0)
    const float* bh    = (const float*)d_in[6];
    const float* wc    = (const float*)d_in[7];
    const float* bg    = (const float*)d_in[8];
    const float* lin_w = (const float*)d_in[9];
    const float* lin_b = (const float*)d_in[10];
    float*       out   = (float*)d_out;

    int n_nodes = in_sizes[0] / FDIM;
    if (n_nodes > MAX_N) n_nodes = MAX_N;
    int E = in_sizes[2];
    if (E > MAX_E) E = MAX_E;

    int nbuck   = (n_nodes + CB - 1) >> CBSH;            // 391 for N=100k
    int per_blk = (((E + NBLK - 1) / NBLK) + 3) & ~3;    // 3128, x4-aligned ranges
    int n_scan  = 2 * nbuck * NBLK + 1;                  // 400385
    int nb_scan = (n_scan + SCAN_TILE - 1) / SCAN_TILE;  // 196 (<= 1024 for scan2)

    hist2_kernel<<<NBLK, 256, 0, stream>>>(ei, E, n_nodes, nbuck, per_blk);
    scan1_kernel<<<nb_scan, 256, 0, stream>>>(n_scan);
    scan2_kernel<<<1, 256, 0, stream>>>(nb_scan);
    scan3_kernel<<<nb_scan, 256, 0, stream>>>(n_scan);
    scatter_burst_kernel<<<NBLK, 256, 0, stream>>>(ei, w, E, n_nodes, nbuck, per_blk);
    deg_sum_kernel<<<nbuck, 256, 0, stream>>>(E, n_nodes, nbuck);
    fine_sort_kernel<<<nbuck, 256, 0, stream>>>(E, n_nodes, nbuck);
    {
        long long tot = (long long)n_nodes * 32;
        gather_kernel<<<(int)((tot + 255) / 256), 256, 0, stream>>>(x, n_nodes);
    }
    gates64_kernel<<<(n_nodes + GNB - 1) / GNB, 256, 0, stream>>>(
        x, Wx, bx, bh, wc, bg, lin_w, lin_b, out, n_nodes);
}

// Round 12
// 254.168 us; speedup vs baseline: 2.4055x; 1.0068x over previous
//
#include <hip/hip_runtime.h>

// LSTM-GCN single step from (H=0, C=0).
// Collapsed math: Fg gate dead (C_prev=0), cheb(H,..)=bh, peephole wc[0],wc[1] dead.
//
// R16: gather is top (51.8 us, FETCH 84MB vs 205MB ideal-L2 traffic, VALU 25%).
// Theory: the 12.8MB CSR stream evicts the 12.8MB x working set from each 4MB
// XCD-L2 (each x row wanted ~16x over kernel life). Fix: NON-TEMPORAL loads
// (nt, evict-first) on the CSR stream + 8-deep unroll with dual accumulators
// (8 independent x-row loads in flight per half-wave, FMA chain split).
// scatter_burst's edge re-read also goes nt (last consumer of ei/w; preserves
// freshly-written record lines in L2 for deg_sum/fine_sort).

#define FDIM 32
#define MAX_N 100000
#define MAX_E 1600000
#define CBSH 8                                // 256 nodes per coarse bucket
#define CB 256
#define MAX_NB ((MAX_N + CB - 1) / CB)        // 391 buckets max
#define NBLK 512                              // blocks in each edge pass
#define SCAN_TILE 2048                        // elements per scan block (256 thr x 8)
#define GNB 64                                // nodes per gates block
#define PERBLK 3136                           // staged records per block (>= 3128)

typedef int   iv4 __attribute__((ext_vector_type(4)));
typedef float fv4 __attribute__((ext_vector_type(4)));
__device__ __forceinline__ iv4 nt_i4(const int* p)   { return __builtin_nontemporal_load((const iv4*)p); }
__device__ __forceinline__ fv4 nt_f4(const float* p) { return __builtin_nontemporal_load((const fv4*)p); }

__device__ float g_deg[MAX_N];                    // dinv (written by deg_sum)
__device__ int   g_part2[2 * MAX_NB * NBLK + 1];  // [dst bins | src bins] counts->offsets
__device__ int   g_blk[1024];                     // scan block sums
__device__ uint2 g_rec[MAX_E];                    // dst-sorted {src<<8|dst_loc, w}
__device__ uint2 g_srec[MAX_E];                   // src-sorted {src_loc, w}
__device__ int   g_row[MAX_N + 1];                // per-node CSR row starts
__device__ __attribute__((aligned(16))) int   g_src2[MAX_E];   // CSR src, node-sorted
__device__ __attribute__((aligned(16))) float g_nrm2[MAX_E];   // CSR nrm, node-sorted
__device__ float g_tx1[MAX_N * FDIM];             // L_hat @ x

// One edge pass, NO global atomics: dual LDS histograms of dst>>8 and src>>8,
// flushed non-atomically to g_part2[bin*NBLK + block]. Edge reads int4 (cached:
// scatter_burst re-reads them later through L3).
__global__ __launch_bounds__(256) void hist2_kernel(const int* __restrict__ ei,
                                                    int E, int n_nodes, int nbuck,
                                                    int per_blk) {
    __shared__ int hd[MAX_NB];
    __shared__ int hs[MAX_NB];
    for (int i = threadIdx.x; i < nbuck; i += 256) { hd[i] = 0; hs[i] = 0; }
    __syncthreads();
    int start = blockIdx.x * per_blk;            // per_blk % 4 == 0 -> aligned
    int end = start + per_blk;
    if (end > E) end = E;
    for (int base = start; base < end; base += 1024) {
        int e = base + threadIdx.x * 4;
        if (e + 4 <= end) {
            int4 s4 = *(const int4*)(ei + e);
            int4 d4 = *(const int4*)(ei + E + e);
#define H2(S, D) if ((unsigned)(S) < (unsigned)n_nodes && (unsigned)(D) < (unsigned)n_nodes) { \
                atomicAdd(&hd[(D) >> CBSH], 1); atomicAdd(&hs[(S) >> CBSH], 1); }
            H2(s4.x, d4.x) H2(s4.y, d4.y) H2(s4.z, d4.z) H2(s4.w, d4.w)
#undef H2
        } else if (e < end) {
            for (int q = e; q < end; ++q) {
                int s = ei[q], d = ei[E + q];
                if ((unsigned)s >= (unsigned)n_nodes || (unsigned)d >= (unsigned)n_nodes)
                    continue;
                atomicAdd(&hd[d >> CBSH], 1);
                atomicAdd(&hs[s >> CBSH], 1);
            }
        }
    }
    __syncthreads();
    for (int i = threadIdx.x; i < nbuck; i += 256) {
        g_part2[i * NBLK + blockIdx.x] = hd[i];
        g_part2[(nbuck + i) * NBLK + blockIdx.x] = hs[i];
    }
    if (blockIdx.x == 0 && threadIdx.x == 0)
        g_part2[2 * nbuck * NBLK] = 0;        // scan sentinel
}

// --- exclusive scan over g_part2[0..n), 3 kernels, VPT=8 (n ~ 400K) ---
__global__ __launch_bounds__(256) void scan1_kernel(int n) {
    __shared__ int sh[256];
    int tid = threadIdx.x;
    int base = blockIdx.x * SCAN_TILE + tid * 8;
    int v[8];
#pragma unroll
    for (int i = 0; i < 8; ++i) v[i] = (base + i < n) ? g_part2[base + i] : 0;
    int tsum = 0;
#pragma unroll
    for (int i = 0; i < 8; ++i) tsum += v[i];
    sh[tid] = tsum;
    __syncthreads();
    for (int off = 1; off < 256; off <<= 1) {
        int t = (tid >= off) ? sh[tid - off] : 0;
        __syncthreads();
        sh[tid] += t;
        __syncthreads();
    }
    if (tid == 255) g_blk[blockIdx.x] = sh[255];
    int run = sh[tid] - tsum;   // exclusive offset within block
#pragma unroll
    for (int i = 0; i < 8; ++i) {
        if (base + i < n) g_part2[base + i] = run;
        run += v[i];
    }
}

__global__ __launch_bounds__(256) void scan2_kernel(int nb) {   // nb <= 1024
    __shared__ int sh[256];
    int tid = threadIdx.x;
    int base = tid * 4;
    int v[4];
#pragma unroll
    for (int i = 0; i < 4; ++i) v[i] = (base + i < nb) ? g_blk[base + i] : 0;
    int tsum = v[0] + v[1] + v[2] + v[3];
    sh[tid] = tsum;
    __syncthreads();
    for (int off = 1; off < 256; off <<= 1) {
        int t = (tid >= off) ? sh[tid - off] : 0;
        __syncthreads();
        sh[tid] += t;
        __syncthreads();
    }
    int run = sh[tid] - tsum;
#pragma unroll
    for (int i = 0; i < 4; ++i) {
        if (base + i < nb) g_blk[base + i] = run;
        run += v[i];
    }
}

__global__ void scan3_kernel(int n) {
    int off = g_blk[blockIdx.x];
    int base = blockIdx.x * SCAN_TILE + threadIdx.x * 8;
#pragma unroll
    for (int i = 0; i < 8; ++i) {
        int idx = base + i;
        if (idx < n) g_part2[idx] += off;
    }
}

// Two phases (dst records into g_rec, src records into g_srec). Per phase:
// counts/bases from the scanned matrix, 512-wide LDS Hillis-Steele for local
// run bases, cursor-scatter into staged LDS + per-record global position,
// then coalesced burst write-out. Edge reads nt (last consumer of ei/w).
__global__ __launch_bounds__(256) void scatter_burst_kernel(const int* __restrict__ ei,
                                                            const float* __restrict__ w,
                                                            int E, int n_nodes, int nbuck,
                                                            int per_blk) {
    __shared__ int   cnt[512];
    __shared__ int   sc[512];
    __shared__ int   gb[MAX_NB];
    __shared__ int   cur[MAX_NB];
    __shared__ uint2 staged[PERBLK];
    __shared__ int   gpos[PERBLK];
    int tid = threadIdx.x;
    int blk = blockIdx.x;
    int start = blk * per_blk;
    int end = start + per_blk;
    if (end > E) end = E;

    for (int phase = 0; phase < 2; ++phase) {
        cnt[tid] = 0; cnt[tid + 256] = 0;
        __syncthreads();
        for (int i = tid; i < nbuck; i += 256) {
            int flat = (phase * nbuck + i) * NBLK + blk;
            int g0 = g_part2[flat];
            int g1 = g_part2[flat + 1];            // flat successor = run end
            gb[i] = g0 - phase * E;                // src space is [E,2E)
            cnt[i] = g1 - g0;
        }
        __syncthreads();
        sc[tid] = cnt[tid]; sc[tid + 256] = cnt[tid + 256];
        __syncthreads();
        for (int off = 1; off < 512; off <<= 1) {  // inclusive scan, 512 wide
            int v0 = (tid >= off) ? sc[tid - off] : 0;
            int v1 = sc[tid + 256 - off];          // tid+256 >= off always
            __syncthreads();
            sc[tid] += v0; sc[tid + 256] += v1;
            __syncthreads();
        }
        for (int i = tid; i < nbuck; i += 256) cur[i] = sc[i] - cnt[i];
        __syncthreads();
#define SB1(S, D, W)                                                            \
        {   int s = (S), d = (D);                                               \
            if ((unsigned)s < (unsigned)n_nodes && (unsigned)d < (unsigned)n_nodes) { \
                int key = phase ? s : d;                                        \
                int bin = key >> CBSH;                                          \
                float w0 = (s == d) ? 0.f : (W);                                \
                unsigned pay = phase ? (unsigned)(s & (CB - 1))                 \
                    : (((unsigned)s << CBSH) | (unsigned)(d & (CB - 1)));       \
                int p = atomicAdd(&cur[bin], 1);                                \
                staged[p] = make_uint2(pay, __float_as_uint(w0));               \
                gpos[p] = gb[bin] + (p - (sc[bin] - cnt[bin]));                 \
            } }
        for (int base = start; base < end; base += 1024) {
            int e = base + tid * 4;
            if (e + 4 <= end) {
                iv4 s4 = nt_i4(ei + e);
                iv4 d4 = nt_i4(ei + E + e);
                fv4 w4 = nt_f4(w + e);
                SB1(s4[0], d4[0], w4[0]) SB1(s4[1], d4[1], w4[1])
                SB1(s4[2], d4[2], w4[2]) SB1(s4[3], d4[3], w4[3])
            } else if (e < end) {
                for (int q = e; q < end; ++q) SB1(ei[q], ei[E + q], w[q])
            }
        }
#undef SB1
        __syncthreads();
        int tot = sc[511];                         // valid records in this chunk
        if (phase == 0) {
            for (int t = tid; t < tot; t += 256) g_rec[gpos[t]] = staged[t];
        } else {
            for (int t = tid; t < tot; t += 256) g_srec[gpos[t]] = staged[t];
        }
        __syncthreads();
    }
}

// One block per src bucket (256 nodes): LDS f32 accumulate w per local node,
// then write dinv = rsqrt(deg) directly. No global atomics.
__global__ __launch_bounds__(256) void deg_sum_kernel(int E, int n_nodes, int nbuck) {
    __shared__ float ldeg[CB];
    int b = blockIdx.x;
    int rs = g_part2[(nbuck + b) * NBLK] - E;
    int re = g_part2[(nbuck + b + 1) * NBLK] - E;   // b==nbuck-1 hits sentinel (2E)
    ldeg[threadIdx.x] = 0.f;
    __syncthreads();
    for (int i = rs + threadIdx.x; i < re; i += 256) {
        uint2 r = g_srec[i];
        atomicAdd(&ldeg[r.x], __uint_as_float(r.y));   // LDS atomic
    }
    __syncthreads();
    int node = (b << CBSH) + threadIdx.x;
    if (node < n_nodes) {
        float dg = ldeg[threadIdx.x];
        g_deg[node] = (dg > 0.f) ? rsqrtf(dg) : 0.f;
    }
}

// One block per dst bucket (256 nodes, ~4096 records): count local nodes (LDS),
// 4-wave hierarchical exclusive scan -> absolute g_row, then reorder records
// into per-node CSR (g_src2/g_nrm2), computing nrm = -dinv[s]*w*dinv[d] on the
// fly (dinv is 400 KB -> L2-resident; bucket-side dinv staged in LDS).
__global__ __launch_bounds__(256) void fine_sort_kernel(int E, int n_nodes, int nbuck) {
    __shared__ int cnt[CB];
    __shared__ int cur[CB];
    __shared__ float dv[CB];
    __shared__ int wsum[4];
    int b = blockIdx.x;
    int rs = g_part2[b * NBLK];
    int re = g_part2[(b + 1) * NBLK];   // b==nbuck-1 hits first src bin (= E)
    {
        int tid = threadIdx.x;
        cnt[tid] = 0;
        int node = (b << CBSH) + tid;
        dv[tid] = (node < n_nodes) ? g_deg[node] : 0.f;
    }
    __syncthreads();
    for (int i = rs + threadIdx.x; i < re; i += 256)
        atomicAdd(&cnt[g_rec[i].x & (CB - 1)], 1);
    __syncthreads();
    {
        int tid = threadIdx.x;
        int lane = tid & 63;
        int wave = tid >> 6;
        int v = cnt[tid];
        int inc = v;
#pragma unroll
        for (int off = 1; off < 64; off <<= 1) {
            int t = __shfl_up(inc, off, 64);
            if (lane >= off) inc += t;
        }
        if (lane == 63) wsum[wave] = inc;
        __syncthreads();
        int wo = 0;
#pragma unroll
        for (int ww = 0; ww < 4; ++ww) wo += (ww < wave) ? wsum[ww] : 0;
        int start = rs + wo + (inc - v);   // exclusive
        cur[tid] = start;
        int node = (b << CBSH) + tid;
        if (node < n_nodes) g_row[node] = start;
    }
    if (b == nbuck - 1 && threadIdx.x == 0) g_row[n_nodes] = re;
    __syncthreads();
    for (int i = rs + threadIdx.x; i < re; i += 256) {
        uint2 r = g_rec[i];
        int s = (int)(r.x >> CBSH);
        int loc = r.x & (CB - 1);
        float nrm = -g_deg[s] * __uint_as_float(r.y) * dv[loc];
        int pos = atomicAdd(&cur[loc], 1);   // LDS atomic
        g_src2[pos] = s;
        g_nrm2[pos] = nrm;
    }
}

// Half-wave (32 lanes = 32 features) per node, REGISTER accumulators (dual, to
// split the FMA chain). CSR stream read NON-TEMPORALLY (evict-first) so it does
// not displace the x working set from L2. 8-deep main unroll = 8 independent
// x-row loads in flight per half-wave; 4-chunk mop-up; scalar tail.
__global__ __launch_bounds__(256) void gather_kernel(const float* __restrict__ x,
                                                     int n_nodes) {
    int t = blockIdx.x * blockDim.x + threadIdx.x;
    int node = t >> 5;
    int f = t & 31;
    if (node >= n_nodes) return;
    int i = g_row[node];
    int end = g_row[node + 1];
    float acc = 0.f, accB = 0.f;
    while (i < end && (i & 3)) {           // peel to 16B alignment
        acc += g_nrm2[i] * x[g_src2[i] * FDIM + f];
        ++i;
    }
    for (; i + 8 <= end; i += 8) {
        iv4 sa = nt_i4(g_src2 + i);
        iv4 sb = nt_i4(g_src2 + i + 4);
        fv4 na = nt_f4(g_nrm2 + i);
        fv4 nb = nt_f4(g_nrm2 + i + 4);
        float xa0 = x[sa[0] * FDIM + f], xa1 = x[sa[1] * FDIM + f];
        float xa2 = x[sa[2] * FDIM + f], xa3 = x[sa[3] * FDIM + f];
        float xb0 = x[sb[0] * FDIM + f], xb1 = x[sb[1] * FDIM + f];
        float xb2 = x[sb[2] * FDIM + f], xb3 = x[sb[3] * FDIM + f];
        acc  += na[0] * xa0 + na[1] * xa1 + na[2] * xa2 + na[3] * xa3;
        accB += nb[0] * xb0 + nb[1] * xb1 + nb[2] * xb2 + nb[3] * xb3;
    }
    for (; i + 4 <= end; i += 4) {
        iv4 s4 = nt_i4(g_src2 + i);
        fv4 n4 = nt_f4(g_nrm2 + i);
        acc += n4[0] * x[s4[0] * FDIM + f] + n4[1] * x[s4[1] * FDIM + f]
             + n4[2] * x[s4[2] * FDIM + f] + n4[3] * x[s4[3] * FDIM + f];
    }
    for (; i < end; ++i) acc += g_nrm2[i] * x[g_src2[i] * FDIM + f];
    g_tx1[node * FDIM + f] = acc + accB;
}

// 64 nodes per 256-thread block. Thread (grp, j) accumulates output feature j
// of gates i,c,o for 8 nodes. k processed in chunks of 4: x/t read as float4
// broadcasts (b128, conflict-free), weights b32 coalesced.
__global__ __launch_bounds__(256, 4) void gates64_kernel(
    const float* __restrict__ x,
    const float* __restrict__ Wx, const float* __restrict__ bx,
    const float* __restrict__ bh, const float* __restrict__ wc,
    const float* __restrict__ bg, const float* __restrict__ lin_w,
    const float* __restrict__ lin_b, float* __restrict__ out, int n_nodes) {
    __shared__ float Ws[3 * 2048];      // gates {i,c,o} x K=2 x 32x32 = 24 KB
    __shared__ float xs[GNB * FDIM];    // 8 KB
    __shared__ float ts[GNB * FDIM];    // 8 KB

    for (int idx = threadIdx.x; idx < 512; idx += 256) {
        *(float4*)&Ws[idx * 4]        = *(const float4*)&Wx[0 * 2048 + idx * 4];
        *(float4*)&Ws[2048 + idx * 4] = *(const float4*)&Wx[2 * 2048 + idx * 4];
        *(float4*)&Ws[4096 + idx * 4] = *(const float4*)&Wx[3 * 2048 + idx * 4];
    }
    int node0 = blockIdx.x * GNB;
    for (int t = threadIdx.x; t < GNB * FDIM / 4; t += 256) {
        int q = t * 4;
        int n = node0 + (q >> 5);
        float4 xv = make_float4(0.f, 0.f, 0.f, 0.f);
        float4 tv = make_float4(0.f, 0.f, 0.f, 0.f);
        if (n < n_nodes) {
            xv = *(const float4*)&x[n * FDIM + (q & 31)];
            tv = *(const float4*)&g_tx1[n * FDIM + (q & 31)];
        }
        *(float4*)&xs[q] = xv;
        *(float4*)&ts[q] = tv;
    }
    __syncthreads();

    int j   = threadIdx.x & 31;
    int grp = threadIdx.x >> 5;         // 0..7, handles nodes grp*8 .. grp*8+7

    float ai0=0.f,ai1=0.f,ai2=0.f,ai3=0.f,ai4=0.f,ai5=0.f,ai6=0.f,ai7=0.f;
    float ac0=0.f,ac1=0.f,ac2=0.f,ac3=0.f,ac4=0.f,ac5=0.f,ac6=0.f,ac7=0.f;
    float ao0=0.f,ao1=0.f,ao2=0.f,ao3=0.f,ao4=0.f,ao5=0.f,ao6=0.f,ao7=0.f;
    const float* xr = &xs[(grp * 8) * FDIM];
    const float* tr = &ts[(grp * 8) * FDIM];
    for (int k4 = 0; k4 < 32; k4 += 4) {
        float4 xv0 = *(const float4*)(xr + 0 * FDIM + k4);
        float4 xv1 = *(const float4*)(xr + 1 * FDIM + k4);
        float4 xv2 = *(const float4*)(xr + 2 * FDIM + k4);
        float4 xv3 = *(const float4*)(xr + 3 * FDIM + k4);
        float4 xv4 = *(const float4*)(xr + 4 * FDIM + k4);
        float4 xv5 = *(const float4*)(xr + 5 * FDIM + k4);
        float4 xv6 = *(const float4*)(xr + 6 * FDIM + k4);
        float4 xv7 = *(const float4*)(xr + 7 * FDIM + k4);
        float4 tv0 = *(const float4*)(tr + 0 * FDIM + k4);
        float4 tv1 = *(const float4*)(tr + 1 * FDIM + k4);
        float4 tv2 = *(const float4*)(tr + 2 * FDIM + k4);
        float4 tv3 = *(const float4*)(tr + 3 * FDIM + k4);
        float4 tv4 = *(const float4*)(tr + 4 * FDIM + k4);
        float4 tv5 = *(const float4*)(tr + 5 * FDIM + k4);
        float4 tv6 = *(const float4*)(tr + 6 * FDIM + k4);
        float4 tv7 = *(const float4*)(tr + 7 * FDIM + k4);
#define KSTEP(kc, COMP)                                        \
        {   int o0 = (k4 + kc) * 32 + j;                       \
            float wi0 = Ws[o0],        wi1 = Ws[1024 + o0];    \
            float wg0 = Ws[2048 + o0], wg1 = Ws[3072 + o0];    \
            float wo0 = Ws[4096 + o0], wo1 = Ws[5120 + o0];    \
            ai0 += xv0.COMP * wi0 + tv0.COMP * wi1;            \
            ac0 += xv0.COMP * wg0 + tv0.COMP * wg1;            \
            ao0 += xv0.COMP * wo0 + tv0.COMP * wo1;            \
            ai1 += xv1.COMP * wi0 + tv1.COMP * wi1;            \
            ac1 += xv1.COMP * wg0 + tv1.COMP * wg1;            \
            ao1 += xv1.COMP * wo0 + tv1.COMP * wo1;            \
            ai2 += xv2.COMP * wi0 + tv2.COMP * wi1;            \
            ac2 += xv2.COMP * wg0 + tv2.COMP * wg1;            \
            ao2 += xv2.COMP * wo0 + tv2.COMP * wo1;            \
            ai3 += xv3.COMP * wi0 + tv3.COMP * wi1;            \
            ac3 += xv3.COMP * wg0 + tv3.COMP * wg1;            \
            ao3 += xv3.COMP * wo0 + tv3.COMP * wo1;            \
            ai4 += xv4.COMP * wi0 + tv4.COMP * wi1;            \
            ac4 += xv4.COMP * wg0 + tv4.COMP * wg1;            \
            ao4 += xv4.COMP * wo0 + tv4.COMP * wo1;            \
            ai5 += xv5.COMP * wi0 + tv5.COMP * wi1;            \
            ac5 += xv5.COMP * wg0 + tv5.COMP * wg1;            \
            ao5 += xv5.COMP * wo0 + tv5.COMP * wo1;            \
            ai6 += xv6.COMP * wi0 + tv6.COMP * wi1;            \
            ac6 += xv6.COMP * wg0 + tv6.COMP * wg1;            \
            ao6 += xv6.COMP * wo0 + tv6.COMP * wo1;            \
            ai7 += xv7.COMP * wi0 + tv7.COMP * wi1;            \
            ac7 += xv7.COMP * wg0 + tv7.COMP * wg1;            \
            ao7 += xv7.COMP * wo0 + tv7.COMP * wo1;            \
        }
        KSTEP(0, x) KSTEP(1, y) KSTEP(2, z) KSTEP(3, w)
#undef KSTEP
    }

    float bi = bx[0 * 32 + j] + bh[0 * 32 + j] + bg[0 * 32 + j];
    float bc = bx[2 * 32 + j] + bh[2 * 32 + j] + bg[2 * 32 + j];
    float bo = bx[3 * 32 + j] + bh[3 * 32 + j] + bg[3 * 32 + j];
    float wcp = wc[2 * 32 + j];
    float lwj = lin_w[j];
    float lb0 = lin_b[0];

#define GOUT(m, AI, AC, AO)                                            \
    {   int n = node0 + grp * 8 + m;                                   \
        float I = 1.f / (1.f + __expf(-(AI + bi)));                    \
        float T = tanhf(AC + bc);                                      \
        float C = I * T;                                               \
        float O = 1.f / (1.f + __expf(-(AO + bo + wcp * C)));          \
        float H = O * tanhf(C);                                        \
        float r = fmaxf(H, 0.f) * lwj;                                 \
        _Pragma("unroll")                                              \
        for (int mm = 16; mm > 0; mm >>= 1) r += __shfl_xor(r, mm, 32);\
        if (j == 0 && n < n_nodes) out[n] = r + lb0; }
    GOUT(0, ai0, ac0, ao0) GOUT(1, ai1, ac1, ao1)
    GOUT(2, ai2, ac2, ao2) GOUT(3, ai3, ac3, ao3)
    GOUT(4, ai4, ac4, ao4) GOUT(5, ai5, ac5, ao5)
    GOUT(6, ai6, ac6, ao6) GOUT(7, ai7, ac7, ao7)
#undef GOUT
}

extern "C" void kernel_launch(void* const* d_in, const int* in_sizes, int n_in,
                              void* d_out, int out_size, void* d_ws, size_t ws_size,
                              hipStream_t stream) {
    const float* x     = (const float*)d_in[0];
    const int*   ei    = (const int*)d_in[1];      // int32 on device
    const float* w     = (const float*)d_in[2];
    const float* Wx    = (const float*)d_in[3];
    const float* bx    = (const float*)d_in[4];
    // d_in[5] = Wh: unused (H=0)
    const float* bh    = (const float*)d_in[6];
    const float* wc    = (const float*)d_in[7];
    const float* bg    = (const float*)d_in[8];
    const float* lin_w = (const float*)d_in[9];
    const float* lin_b = (const float*)d_in[10];
    float*       out   = (float*)d_out;

    int n_nodes = in_sizes[0] / FDIM;
    if (n_nodes > MAX_N) n_nodes = MAX_N;
    int E = in_sizes[2];
    if (E > MAX_E) E = MAX_E;

    int nbuck   = (n_nodes + CB - 1) >> CBSH;            // 391 for N=100k
    int per_blk = (((E + NBLK - 1) / NBLK) + 3) & ~3;    // 3128, x4-aligned ranges
    int n_scan  = 2 * nbuck * NBLK + 1;                  // 400385
    int nb_scan = (n_scan + SCAN_TILE - 1) / SCAN_TILE;  // 196 (<= 1024 for scan2)

    hist2_kernel<<<NBLK, 256, 0, stream>>>(ei, E, n_nodes, nbuck, per_blk);
    scan1_kernel<<<nb_scan, 256, 0, stream>>>(n_scan);
    scan2_kernel<<<1, 256, 0, stream>>>(nb_scan);
    scan3_kernel<<<nb_scan, 256, 0, stream>>>(n_scan);
    scatter_burst_kernel<<<NBLK, 256, 0, stream>>>(ei, w, E, n_nodes, nbuck, per_blk);
    deg_sum_kernel<<<nbuck, 256, 0, stream>>>(E, n_nodes, nbuck);
    fine_sort_kernel<<<nbuck, 256, 0, stream>>>(E, n_nodes, nbuck);
    {
        long long tot = (long long)n_nodes * 32;
        gather_kernel<<<(int)((tot + 255) / 256), 256, 0, stream>>>(x, n_nodes);
    }
    gates64_kernel<<<(n_nodes + GNB - 1) / GNB, 256, 0, stream>>>(
        x, Wx, bx, bh, wc, bg, lin_w, lin_b, out, n_nodes);
}